// Round 5
// baseline (6501.912 us; speedup 1.0000x reference)
//
#include <hip/hip_runtime.h>
#include <math.h>

// ---------------------------------------------------------------------------
// Seq2Seq LSTM (S=128,B=64,I=H=O=1024,L=2,T=64) on gfx950.
// Round 11: de-congest the persistent-decoder barrier. R10 (no fence) still
// cost 21 us/interval with FETCH inflated by ~4MB/stage: 255 spinners on ONE
// 'go' line + 256 arrive slots in 16 lines -> coherence-point queueing on the
// critical stores, and the polls themselves are HBM fetch traffic. Changes:
//  - arrive slots spaced 64B: every arrival store / master poll lane owns a
//    private cacheline (zero sharing, 255 parallel).
//  - 'go' replicated x64 (64B apart): block j polls copy j&63 (<=4 pollers
//    per line); master broadcasts via 64 lanes in parallel.
// Data path unchanged from R10 (passed): write-once D0[t]/H1[t] staging,
// sc0sc1 producer stores, PLAIN cached consumer loads, no fence, weights in
// VGPRs (128/thread), c-state + biases in registers. Encoder unchanged.
// ---------------------------------------------------------------------------

typedef unsigned short u16;
typedef short short8 __attribute__((ext_vector_type(8)));
typedef float f32x4 __attribute__((ext_vector_type(4)));

#define MFMA_BF16 __builtin_amdgcn_mfma_f32_16x16x32_bf16

__device__ __forceinline__ u16 f2bf(float x) {
  unsigned u = __builtin_bit_cast(unsigned, x);
  unsigned r = u + 0x7fffu + ((u >> 16) & 1u);
  return (u16)(r >> 16);
}
__device__ __forceinline__ float bf2f(u16 b) {
  return __builtin_bit_cast(float, ((unsigned)b) << 16);
}
__device__ __forceinline__ int permrow(int r) {
  int gate = r >> 10, hc = r & 1023;
  return ((hc >> 2) << 4) + ((hc & 3) << 2) + gate;
}

// write-through store: commits at the device coherence point
__device__ __forceinline__ void st_sc(u16* p, u16 v) {
  unsigned vv = v;
  asm volatile("global_store_short %0, %1, off sc0 sc1" :: "v"(p), "v"(vv) : "memory");
}
// coherent (coherence-point) load/store for barrier words
__device__ __forceinline__ int coh_load(const int* p) {
  int v;
  asm volatile("global_load_dword %0, %1, off sc0 sc1\n\ts_waitcnt vmcnt(0)"
               : "=v"(v) : "v"(p) : "memory");
  return v;
}
__device__ __forceinline__ void coh_store(int* p, int v) {
  asm volatile("global_store_dword %0, %1, off sc0 sc1\n\ts_waitcnt vmcnt(0)"
               :: "v"(p), "v"(v) : "memory");
}

// ---------------- prep kernels ----------------

// mode 0: plain; mode 1: transpose (1024x1024); mode 2: permute 4096 rows
__global__ void split_mat(const float* __restrict__ src, u16* __restrict__ dh,
                          u16* __restrict__ dl, int n, int mode) {
  int i = blockIdx.x * 256 + threadIdx.x;
  if (i >= n) return;
  float v = src[i];
  u16 hi = f2bf(v);
  u16 lo = f2bf(v - bf2f(hi));
  int r = i >> 10, c = i & 1023;
  int idx = i;
  if (mode == 1) idx = c * 1024 + r;
  else if (mode == 2) idx = permrow(r) * 1024 + c;
  dh[idx] = hi; dl[idx] = lo;
}

__global__ void zero_f4(float4* __restrict__ p, int n) {
  int i = blockIdx.x * 256 + threadIdx.x;
  if (i < n) p[i] = make_float4(0.f, 0.f, 0.f, 0.f);
}

__global__ void bias_perm(const float* __restrict__ in, float* __restrict__ out) {
  int i = blockIdx.x * 256 + threadIdx.x;
  if (i < 4096) out[permrow(i)] = in[i];
}

// bcomb[perm(n)] = dec_b0[n] + sum_k lin_b[k] * dec_wih0[n][k]
__global__ void bias_comb(const float* __restrict__ db0, const float* __restrict__ lb,
                          const float* __restrict__ wih, float* __restrict__ out) {
  __shared__ float red[256];
  int n = blockIdx.x;
  float s = 0.f;
  for (int k = threadIdx.x; k < 1024; k += 256) s += lb[k] * wih[(size_t)n * 1024 + k];
  red[threadIdx.x] = s;
  __syncthreads();
  for (int d = 128; d > 0; d >>= 1) {
    if (threadIdx.x < d) red[threadIdx.x] += red[threadIdx.x + d];
    __syncthreads();
  }
  if (threadIdx.x == 0) out[permrow(n)] = db0[n] + red[0];
}

// ---------- split-bf16 GEMM: C[M,N] = A[M,K] * B[N,K]^T ----------
// Block: (64*MT) M-rows x 128 N-cols; 4 waves x 2 N-tiles. gn = N/128.
// mode 0: split-bf16 C; mode 1: fp32+bias, row=(t*64+b)->out[b][t][col];
// mode 2: plain fp32 C.
template<int MT>
__global__ __launch_bounds__(256) void gemm_split(
    const u16* __restrict__ Ah, const u16* __restrict__ Al, int lda,
    const u16* __restrict__ Bh, const u16* __restrict__ Bl, int ldb,
    int K, int gn,
    u16* __restrict__ Ch, u16* __restrict__ Cl, int ldc,
    float* __restrict__ outp, const float* __restrict__ bias, int ldout, int mode) {
  int bm = blockIdx.x / gn, bn = blockIdx.x % gn;
  int l = threadIdx.x & 63, w = threadIdx.x >> 6;
  int n0 = bn * 128 + w * 32;
  int rr = l & 15, ko = (l >> 4) << 3, q = l >> 4;
  int M0 = bm * 64 * MT;
  f32x4 acc[8 * MT] = {};
  for (int kk = 0; kk < K; kk += 32) {
    short8 bh[2], bl[2];
#pragma unroll
    for (int nt = 0; nt < 2; ++nt) {
      size_t bo = (size_t)(n0 + nt * 16 + rr) * ldb + kk + ko;
      bh[nt] = *(const short8*)(Bh + bo);
      bl[nt] = *(const short8*)(Bl + bo);
    }
#pragma unroll
    for (int mt = 0; mt < 4 * MT; ++mt) {
      size_t ao = (size_t)(M0 + mt * 16 + rr) * lda + kk + ko;
      short8 ah = *(const short8*)(Ah + ao);
      short8 al = *(const short8*)(Al + ao);
#pragma unroll
      for (int nt = 0; nt < 2; ++nt) {
        f32x4 t = acc[mt * 2 + nt];
        t = MFMA_BF16(ah, bh[nt], t, 0, 0, 0);
        t = MFMA_BF16(ah, bl[nt], t, 0, 0, 0);
        t = MFMA_BF16(al, bh[nt], t, 0, 0, 0);
        acc[mt * 2 + nt] = t;
      }
    }
  }
#pragma unroll
  for (int mt = 0; mt < 4 * MT; ++mt)
#pragma unroll
    for (int nt = 0; nt < 2; ++nt)
#pragma unroll
      for (int r = 0; r < 4; ++r) {
        int row = M0 + mt * 16 + q * 4 + r;
        int col = n0 + nt * 16 + rr;
        float v = acc[mt * 2 + nt][r];
        if (mode == 0) {
          u16 hh = f2bf(v);
          Ch[(size_t)row * ldc + col] = hh;
          Cl[(size_t)row * ldc + col] = f2bf(v - bf2f(hh));
        } else if (mode == 1) {
          int t = row >> 6, b = row & 63;
          outp[(size_t)b * 65536 + t * 1024 + col] = v + bias[col];
        } else {
          outp[(size_t)row * ldout + col] = v;
        }
      }
}

// ---------------- encoder paired step kernel ----------------

struct Half {
  const u16 *Ah, *Al, *Wh, *Wl;
  const float* pre;    // fp32 [64][4096] gate slab
  const float* bias;   // permuted [4096]
  float* c;
  u16 *Hh, *Hl;
  int active;
};

__global__ __launch_bounds__(512, 1) void lstm_pair(Half hA, Half hB) {
  int j = blockIdx.x;
  Half S = (j < 128) ? hA : hB;
  if (!S.active) return;
  int sub = j & 127;
  int rowblk = ((sub & 7) << 4) | (sub >> 3);   // XCD-pinned, 0..127
  int R = rowblk << 5;                           // 32 rows
  int tid = threadIdx.x;
  int l = tid & 63, w = tid >> 6;
  int rr = l & 15, ko = (l >> 4) << 3, q = l >> 4;
  int kb = w << 7;                               // 128-wide K slice
  const u16* __restrict__ Wh = S.Wh + (size_t)(R + rr) * 1024 + kb + ko;
  const u16* __restrict__ Wl = S.Wl + (size_t)(R + rr) * 1024 + kb + ko;
  const u16* __restrict__ Ah = S.Ah + kb + ko;
  const u16* __restrict__ Al = S.Al + kb + ko;

  f32x4 acc[8] = {};
#pragma unroll
  for (int kk = 0; kk < 128; kk += 32) {
    short8 bh[2], bl[2];
#pragma unroll
    for (int nt = 0; nt < 2; ++nt) {
      bh[nt] = *(const short8*)(Wh + (size_t)(nt << 4) * 1024 + kk);
      bl[nt] = *(const short8*)(Wl + (size_t)(nt << 4) * 1024 + kk);
    }
#pragma unroll
    for (int mt = 0; mt < 4; ++mt) {
      size_t ao = (size_t)((mt << 4) + rr) * 1024 + kk;
      short8 ah = *(const short8*)(Ah + ao);
      short8 al = *(const short8*)(Al + ao);
#pragma unroll
      for (int nt = 0; nt < 2; ++nt) {
        f32x4 t = acc[mt * 2 + nt];
        t = MFMA_BF16(ah, bh[nt], t, 0, 0, 0);
        t = MFMA_BF16(ah, bl[nt], t, 0, 0, 0);
        t = MFMA_BF16(al, bh[nt], t, 0, 0, 0);
        acc[mt * 2 + nt] = t;
      }
    }
  }

  __shared__ float lds[8][64][33];
#pragma unroll
  for (int mt = 0; mt < 4; ++mt)
#pragma unroll
    for (int nt = 0; nt < 2; ++nt)
#pragma unroll
      for (int r = 0; r < 4; ++r)
        lds[w][(mt << 4) + (q << 2) + r][(nt << 4) + rr] = acc[mt * 2 + nt][r];
  __syncthreads();

  int b = tid >> 3, e = tid & 7;
  float g[4];
#pragma unroll
  for (int gt = 0; gt < 4; ++gt) {
    int c = (e << 2) + gt;
    float s = S.bias[R + c] + S.pre[(size_t)b * 4096 + R + c];
#pragma unroll
    for (int ww = 0; ww < 8; ++ww) s += lds[ww][b][c];
    g[gt] = s;
  }
  int hc = (rowblk << 3) + e;
  size_t ci = (size_t)b * 1024 + hc;
  float cold = S.c[ci];
  float is = 1.f / (1.f + expf(-g[0]));
  float fs = 1.f / (1.f + expf(-g[1]));
  float gg = tanhf(g[2]);
  float os = 1.f / (1.f + expf(-g[3]));
  float cn = fs * cold + is * gg;
  S.c[ci] = cn;
  float h = os * tanhf(cn);
  S.Hh[ci] = f2bf(h);
  S.Hl[ci] = f2bf(h - bf2f(f2bf(h)));
}

// ---------------- persistent decoder megakernel ----------------
// 256 blocks x 512 thr, all co-resident (1 block/CU). Block = 16 perm-rows.
// Weights for BOTH stages live in registers across all 64 steps.
// Write-once staging (D0[t], H1[t]) -> plain cached consumer loads, no fence.
// Barrier layout (ints, 16-int = 64B spacing):
//   arrive slot j  : bar[j*16]          (j=1..255, private line each)
//   go copy g      : bar[4096 + g*16]   (g=0..63, <=4 pollers each)

struct DecP {
  const u16 *Wch, *Wcl;      // Wcomb     (stage A, op0; A-operand h1prev)
  const u16 *W0h, *W0l;      // WhhD0     (stage A, op1; A-operand h0prev)
  const u16 *Wi1h, *Wi1l;    // WihD1     (stage B, op0; A-operand d0 cur)
  const u16 *Wh1h, *Wh1l;    // WhhD1     (stage B, op1; A-operand h1prev)
  const u16 *h0i_h, *h0i_l;  // encoder L0 final h
  const u16 *h1i_h, *h1i_l;  // encoder L1 final h
  const u16 *zh, *zl;        // zeros (t=0 stage A op0 operand)
  const float *Gd0, *dbp0, *bdec0, *dbp1;
  const float *c0, *c1;      // encoder final c (read once)
  u16 *D0h, *D0l;            // write-once [64*65536]
  u16 *H1h, *H1l;            // write-once [64*65536]
  int* bar;                  // [8192] pre-zeroed
};

// flat master/slot barrier, NO cache maintenance, NO shared poll lines:
// block j!=0 stores seq to its private arrive line, then spins on go copy
// j&63. Block 0's lanes 1..255 each poll one private arrive line; then 64
// lanes broadcast the 64 go copies in parallel.
__device__ __forceinline__ void gridbar(int* bar, int seq, int j) {
  __syncthreads();   // drains every wave's vmem (incl. sc1 data stores)
  int tid = threadIdx.x;
  if (j == 0) {
    if (tid >= 1 && tid < 256) {
      const int* p = bar + (tid << 4);
      while (coh_load(p) < seq) __builtin_amdgcn_s_sleep(2);
    }
    __syncthreads();
    if (tid < 64) coh_store(bar + 4096 + (tid << 4), seq);
  } else {
    if (tid == 0) {
      coh_store(bar + (j << 4), seq);
      const int* p = bar + 4096 + ((j & 63) << 4);
      while (coh_load(p) < seq) __builtin_amdgcn_s_sleep(2);
    }
  }
  __syncthreads();
}

__global__ __launch_bounds__(512, 1) void lstm_dec_persist(DecP D) {
  int j = blockIdx.x;
  int rowblk = ((j & 7) << 5) | (j >> 3);      // XCD-pinned, 0..255
  int R = rowblk << 4;                          // 16 rows
  int tid = threadIdx.x;
  int l = tid & 63, w = tid >> 6;
  int rr = l & 15, ko = (l >> 4) << 3, q = l >> 4;
  int opidx = w >> 2;                           // waves 0-3: op0, 4-7: op1
  int kb = (w & 3) << 8;                        // 256-wide K slice
  size_t woff = (size_t)(R + rr) * 1024 + kb + ko;
  int* bar = D.bar;

  // ---- preload both stages' weight fragments into registers ----
  const u16* pWAh = (opidx == 0 ? D.Wch : D.W0h) + woff;
  const u16* pWAl = (opidx == 0 ? D.Wcl : D.W0l) + woff;
  const u16* pWBh = (opidx == 0 ? D.Wi1h : D.Wh1h) + woff;
  const u16* pWBl = (opidx == 0 ? D.Wi1l : D.Wh1l) + woff;
  short8 wAh[8], wAl[8], wBh[8], wBl[8];
#pragma unroll
  for (int ki = 0; ki < 8; ++ki) {
    wAh[ki] = *(const short8*)(pWAh + (ki << 5));
    wAl[ki] = *(const short8*)(pWAl + (ki << 5));
    wBh[ki] = *(const short8*)(pWBh + (ki << 5));
    wBl[ki] = *(const short8*)(pWBl + (ki << 5));
  }

  // ---- tail-thread private state: c, biases (live in regs for 64 steps) ---
  float creg0 = 0.f, creg1 = 0.f;
  float bA[4], bB[4], gb0[4];
  size_t ci = 0;
  if (tid < 256) {
    int b = tid >> 2, e = tid & 3;
    int hc = (rowblk << 2) + e;
    ci = (size_t)b * 1024 + hc;
    creg0 = D.c0[ci];
    creg1 = D.c1[ci];
#pragma unroll
    for (int gt = 0; gt < 4; ++gt) {
      int cc = R + (e << 2) + gt;
      bA[gt] = D.bdec0[cc];
      bB[gt] = D.dbp1[cc];
      gb0[gt] = D.dbp0[cc] + D.Gd0[(size_t)(tid >> 2) * 4096 + cc];
    }
  }

  __shared__ float lds[8][64][17];
  const u16 *h0p_h = D.h0i_h, *h0p_l = D.h0i_l;   // h0(t-1)
  int seq = 0;

  for (int t = 0; t < 64; ++t) {
    u16* d0c_h = D.D0h + (size_t)t * 65536;
    u16* d0c_l = D.D0l + (size_t)t * 65536;
    const u16* h1p_h = (t == 0) ? D.h1i_h : D.H1h + (size_t)(t - 1) * 65536;
    const u16* h1p_l = (t == 0) ? D.h1i_l : D.H1l + (size_t)(t - 1) * 65536;

    // ======== stage A: gates0 = Wcomb*h1prev(+0 at t=0) + WhhD0*h0prev ====
    {
      const u16* Aph = (opidx == 0) ? (t == 0 ? D.zh : h1p_h) : h0p_h;
      const u16* Apl = (opidx == 0) ? (t == 0 ? D.zl : h1p_l) : h0p_l;
      const u16* __restrict__ Ah_ = Aph + kb + ko;
      const u16* __restrict__ Al_ = Apl + kb + ko;
      f32x4 acc[4] = {};
#pragma unroll
      for (int ki = 0; ki < 8; ++ki) {
#pragma unroll
        for (int mt = 0; mt < 4; ++mt) {
          size_t ao = (size_t)((mt << 4) + rr) * 1024 + (ki << 5);
          short8 ah = *(const short8*)(Ah_ + ao);
          short8 al = *(const short8*)(Al_ + ao);
          acc[mt] = MFMA_BF16(ah, wAh[ki], acc[mt], 0, 0, 0);
          acc[mt] = MFMA_BF16(ah, wAl[ki], acc[mt], 0, 0, 0);
          acc[mt] = MFMA_BF16(al, wAh[ki], acc[mt], 0, 0, 0);
        }
      }
#pragma unroll
      for (int mt = 0; mt < 4; ++mt)
#pragma unroll
        for (int r = 0; r < 4; ++r)
          lds[w][(mt << 4) + (q << 2) + r][rr] = acc[mt][r];
    }
    __syncthreads();
    if (tid < 256) {
      int b = tid >> 2, e = tid & 3;
      float g[4];
#pragma unroll
      for (int gt = 0; gt < 4; ++gt) {
        int c = (e << 2) + gt;
        float s = (t == 0) ? gb0[gt] : bA[gt];
#pragma unroll
        for (int ww = 0; ww < 8; ++ww) s += lds[ww][b][c];
        g[gt] = s;
      }
      float is = 1.f / (1.f + expf(-g[0]));
      float fs = 1.f / (1.f + expf(-g[1]));
      float gg = tanhf(g[2]);
      float os = 1.f / (1.f + expf(-g[3]));
      float cn = fs * creg0 + is * gg;
      creg0 = cn;
      float h = os * tanhf(cn);
      u16 hh = f2bf(h);
      st_sc(d0c_h + ci, hh);
      st_sc(d0c_l + ci, f2bf(h - bf2f(hh)));
    }
    gridbar(bar, ++seq, j);   // d0(t) now at coherence point

    // ======== stage B: gates1 = WihD1*d0(t) + WhhD1*h1prev ========
    {
      const u16* Aph = (opidx == 0) ? d0c_h : h1p_h;
      const u16* Apl = (opidx == 0) ? d0c_l : h1p_l;
      const u16* __restrict__ Ah_ = Aph + kb + ko;
      const u16* __restrict__ Al_ = Apl + kb + ko;
      f32x4 acc[4] = {};
#pragma unroll
      for (int ki = 0; ki < 8; ++ki) {
#pragma unroll
        for (int mt = 0; mt < 4; ++mt) {
          size_t ao = (size_t)((mt << 4) + rr) * 1024 + (ki << 5);
          short8 ah = *(const short8*)(Ah_ + ao);
          short8 al = *(const short8*)(Al_ + ao);
          acc[mt] = MFMA_BF16(ah, wBh[ki], acc[mt], 0, 0, 0);
          acc[mt] = MFMA_BF16(ah, wBl[ki], acc[mt], 0, 0, 0);
          acc[mt] = MFMA_BF16(al, wBh[ki], acc[mt], 0, 0, 0);
        }
      }
#pragma unroll
      for (int mt = 0; mt < 4; ++mt)
#pragma unroll
        for (int r = 0; r < 4; ++r)
          lds[w][(mt << 4) + (q << 2) + r][rr] = acc[mt][r];
    }
    __syncthreads();
    if (tid < 256) {
      int b = tid >> 2, e = tid & 3;
      float g[4];
#pragma unroll
      for (int gt = 0; gt < 4; ++gt) {
        int c = (e << 2) + gt;
        float s = bB[gt];
#pragma unroll
        for (int ww = 0; ww < 8; ++ww) s += lds[ww][b][c];
        g[gt] = s;
      }
      float is = 1.f / (1.f + expf(-g[0]));
      float fs = 1.f / (1.f + expf(-g[1]));
      float gg = tanhf(g[2]);
      float os = 1.f / (1.f + expf(-g[3]));
      float cn = fs * creg1 + is * gg;
      creg1 = cn;
      float h = os * tanhf(cn);
      u16 hh = f2bf(h);
      u16 hl = f2bf(h - bf2f(hh));
      size_t hidx = (size_t)t * 65536 + ci;
      st_sc(D.H1h + hidx, hh);
      st_sc(D.H1l + hidx, hl);
    }
    if (t != 63) gridbar(bar, ++seq, j);  // h1(t) visible

    h0p_h = d0c_h; h0p_l = d0c_l;
  }
}

// ---------------- host ----------------

extern "C" void kernel_launch(void* const* d_in, const int* in_sizes, int n_in,
                              void* d_out, int out_size, void* d_ws, size_t ws_size,
                              hipStream_t stream) {
  (void)in_sizes; (void)n_in; (void)out_size; (void)ws_size;
  const float* input_seq = (const float*)d_in[0];
  const float* enc_wih   = (const float*)d_in[1];
  const float* enc_whh   = (const float*)d_in[2];
  const float* enc_b     = (const float*)d_in[3];
  const float* dec_wih   = (const float*)d_in[4];
  const float* dec_whh   = (const float*)d_in[5];
  const float* dec_b     = (const float*)d_in[6];
  const float* lin_w     = (const float*)d_in[7];
  const float* lin_b     = (const float*)d_in[8];
  float* out = (float*)d_out;

  const size_t WE = 4096ull * 1024;
  const size_t HB = 64ull * 1024;
  char* ws = (char*)d_ws;
  size_t off = 0;
  auto alloc16 = [&](size_t elems) {
    u16* p = (u16*)(ws + off);
    off = (off + elems * 2 + 255) & ~(size_t)255;
    return p;
  };
  auto allocf = [&](size_t elems) {
    float* p = (float*)(ws + off);
    off = (off + elems * 4 + 255) & ~(size_t)255;
    return p;
  };

  // weights (permuted rows) split hi/lo: 9 pairs x 16 MB = 144 MB
  u16 *WihE0h = alloc16(WE), *WihE0l = alloc16(WE);
  u16 *WhhE0h = alloc16(WE), *WhhE0l = alloc16(WE);
  u16 *WihE1h = alloc16(WE), *WihE1l = alloc16(WE);
  u16 *WhhE1h = alloc16(WE), *WhhE1l = alloc16(WE);
  u16 *WihD0h = alloc16(WE), *WihD0l = alloc16(WE);
  u16 *WhhD0h = alloc16(WE), *WhhD0l = alloc16(WE);
  u16 *WihD1h = alloc16(WE), *WihD1l = alloc16(WE);
  u16 *WhhD1h = alloc16(WE), *WhhD1l = alloc16(WE);
  u16 *Wcombh = alloc16(WE), *Wcombl = alloc16(WE);
  u16 *WLh  = alloc16(1024 * 1024), *WLl  = alloc16(1024 * 1024);
  u16 *WLTh = alloc16(1024 * 1024), *WLTl = alloc16(1024 * 1024);
  u16 *XCh = alloc16(16 * HB), *XCl = alloc16(16 * HB);     // x chunk
  u16 *XLh = alloc16(HB), *XLl = alloc16(HB);               // x_last
  u16 *H0ch = alloc16(17 * HB), *H0cl = alloc16(17 * HB);   // h0 ring
  u16 *H1h = alloc16(64 * HB), *H1l = alloc16(64 * HB);     // dec h1 history
  u16 *D0h = alloc16(64 * HB), *D0l = alloc16(64 * HB);     // dec d0 write-once
  // zero region
  size_t zbeg = off;
  u16 *zh = alloc16(HB), *zl = alloc16(HB);
  float *c0 = allocf(HB), *c1 = allocf(HB);
  int *barbuf = (int*)(ws + off);
  off = (off + 8192 * sizeof(int) + 255) & ~(size_t)255;
  size_t zend = off;
  // ping-pong h slots (encoder L1)
  u16 *e1h = alloc16(2 * HB), *e1l = alloc16(2 * HB);
  // gate buffers (fp32)
  float *G0 = allocf(1024ull * 4096);   // 16 MB
  float *G1 = allocf(1024ull * 4096);   // 16 MB
  float *Gd0 = allocf(64 * 4096);
  // biases
  float *ebp0 = allocf(4096), *ebp1 = allocf(4096);
  float *dbp0 = allocf(4096), *dbp1 = allocf(4096);
  float *bdec0 = allocf(4096);
  // total ~229 MB

  // 1) zeros (incl. barrier slots)
  {
    int n4 = (int)((zend - zbeg) / 16);
    zero_f4<<<dim3((n4 + 255) / 256), dim3(256), 0, stream>>>((float4*)(ws + zbeg), n4);
  }
  // 2) splits
  auto split = [&](const float* src, u16* dh, u16* dl, int n, int mode) {
    split_mat<<<dim3((n + 255) / 256), dim3(256), 0, stream>>>(src, dh, dl, n, mode);
  };
  split(enc_wih,        WihE0h, WihE0l, (int)WE, 2);
  split(enc_whh,        WhhE0h, WhhE0l, (int)WE, 2);
  split(enc_wih + WE,   WihE1h, WihE1l, (int)WE, 2);
  split(enc_whh + WE,   WhhE1h, WhhE1l, (int)WE, 2);
  split(dec_wih,        WihD0h, WihD0l, (int)WE, 2);
  split(dec_whh,        WhhD0h, WhhD0l, (int)WE, 2);
  split(dec_wih + WE,   WihD1h, WihD1l, (int)WE, 2);
  split(dec_whh + WE,   WhhD1h, WhhD1l, (int)WE, 2);
  split(lin_w, WLh,  WLl,  1024 * 1024, 0);
  split(lin_w, WLTh, WLTl, 1024 * 1024, 1);
  split(input_seq + 127ull * HB, XLh, XLl, (int)HB, 0);
  // 3) biases
  bias_perm<<<dim3(16), dim3(256), 0, stream>>>(enc_b,        ebp0);
  bias_perm<<<dim3(16), dim3(256), 0, stream>>>(enc_b + 4096, ebp1);
  bias_perm<<<dim3(16), dim3(256), 0, stream>>>(dec_b,        dbp0);
  bias_perm<<<dim3(16), dim3(256), 0, stream>>>(dec_b + 4096, dbp1);
  bias_comb<<<dim3(4096), dim3(256), 0, stream>>>(dec_b, lin_b, dec_wih, bdec0);
  // 4) Wcomb = WihD0(perm) @ lin_w : M=4096,N=1024 -> 32x8 blocks
  gemm_split<2><<<dim3(32 * 8), dim3(256), 0, stream>>>(
      WihD0h, WihD0l, 1024, WLTh, WLTl, 1024, 1024, 8,
      Wcombh, Wcombl, 1024, nullptr, nullptr, 0, 0);
  // 4b) Gd0 = x_last @ WihD0^T : M=64,N=4096 -> 1x32 blocks
  gemm_split<1><<<dim3(32), dim3(256), 0, stream>>>(
      XLh, XLl, 1024, WihD0h, WihD0l, 1024, 1024, 32,
      nullptr, nullptr, 0, Gd0, nullptr, 4096, 2);

  // 5) encoder: chunk ch: G0 gemm; paired steps L0(ch)+L1(ch-1); G1 gemm.
  for (int ch = 0; ch < 8; ++ch) {
    split(input_seq + (size_t)ch * 16 * HB, XCh, XCl, (int)(16 * HB), 0);
    gemm_split<2><<<dim3(8 * 32), dim3(256), 0, stream>>>(
        XCh, XCl, 1024, WihE0h, WihE0l, 1024, 1024, 32,
        nullptr, nullptr, 0, G0, nullptr, 4096, 2);
    for (int lt = 0; lt < 16; ++lt) {
      int t0 = ch * 16 + lt;               // L0 step index
      int t1 = (ch - 1) * 16 + lt;         // L1 step index (lagged)
      Half A;
      A.Ah = (t0 == 0) ? zh : (lt == 0 ? H0ch + 16ull * HB : H0ch + (size_t)lt * HB);
      A.Al = (t0 == 0) ? zl : (lt == 0 ? H0cl + 16ull * HB : H0cl + (size_t)lt * HB);
      A.Wh = WhhE0h; A.Wl = WhhE0l;
      A.pre = G0 + (size_t)lt * 64 * 4096;
      A.bias = ebp0; A.c = c0;
      A.Hh = H0ch + (size_t)(lt + 1) * HB; A.Hl = H0cl + (size_t)(lt + 1) * HB;
      A.active = 1;
      Half B;
      B.Ah = (t1 == 0) ? zh : e1h + (size_t)((t1 - 1) & 1) * HB;
      B.Al = (t1 == 0) ? zl : e1l + (size_t)((t1 - 1) & 1) * HB;
      B.Wh = WhhE1h; B.Wl = WhhE1l;
      B.pre = G1 + (size_t)lt * 64 * 4096;
      B.bias = ebp1; B.c = c1;
      B.Hh = e1h + (size_t)((t1 >= 0 ? t1 : 0) & 1) * HB;
      B.Hl = e1l + (size_t)((t1 >= 0 ? t1 : 0) & 1) * HB;
      B.active = (ch >= 1) ? 1 : 0;
      lstm_pair<<<dim3(256), dim3(512), 0, stream>>>(A, B);
    }
    gemm_split<2><<<dim3(8 * 32), dim3(256), 0, stream>>>(
        H0ch + HB, H0cl + HB, 1024, WihE1h, WihE1l, 1024, 1024, 32,
        nullptr, nullptr, 0, G1, nullptr, 4096, 2);
  }
  // drain: L1 steps for ch=7 (t1 = 112..127)
  for (int lt = 0; lt < 16; ++lt) {
    int t1 = 112 + lt;
    Half A; A.active = 0;
    A.Ah = zh; A.Al = zl; A.Wh = WhhE0h; A.Wl = WhhE0l;
    A.pre = G0; A.bias = ebp0; A.c = c0; A.Hh = H0ch; A.Hl = H0cl;
    Half B;
    B.Ah = e1h + (size_t)((t1 - 1) & 1) * HB;
    B.Al = e1l + (size_t)((t1 - 1) & 1) * HB;
    B.Wh = WhhE1h; B.Wl = WhhE1l;
    B.pre = G1 + (size_t)lt * 64 * 4096;
    B.bias = ebp1; B.c = c1;
    B.Hh = e1h + (size_t)(t1 & 1) * HB;
    B.Hl = e1l + (size_t)(t1 & 1) * HB;
    B.active = 1;
    lstm_pair<<<dim3(256), dim3(512), 0, stream>>>(A, B);
  }

  // 6) decoder: ONE persistent kernel, 64 steps x 2 stages, 127 grid barriers
  {
    DecP P;
    P.Wch = Wcombh; P.Wcl = Wcombl;
    P.W0h = WhhD0h; P.W0l = WhhD0l;
    P.Wi1h = WihD1h; P.Wi1l = WihD1l;
    P.Wh1h = WhhD1h; P.Wh1l = WhhD1l;
    P.h0i_h = H0ch + 16ull * HB; P.h0i_l = H0cl + 16ull * HB;
    P.h1i_h = e1h + HB; P.h1i_l = e1l + HB;
    P.zh = zh; P.zl = zl;
    P.Gd0 = Gd0; P.dbp0 = dbp0; P.bdec0 = bdec0; P.dbp1 = dbp1;
    P.c0 = c0; P.c1 = c1;
    P.D0h = D0h; P.D0l = D0l;
    P.H1h = H1h; P.H1l = H1l;
    P.bar = barbuf;
    lstm_dec_persist<<<dim3(256), dim3(512), 0, stream>>>(P);
  }

  // 7) y[b][t][o] = H1[t*64+b][:] . lin_w[o][:] + lin_b[o] : M=4096,N=1024
  gemm_split<2><<<dim3(32 * 8), dim3(256), 0, stream>>>(
      H1h, H1l, 1024, WLh, WLl, 1024, 1024, 8,
      nullptr, nullptr, 0, out, lin_b, 1024, 1);
}

// Round 6
// 6441.407 us; speedup vs baseline: 1.0094x; 1.0094x over previous
//
#include <hip/hip_runtime.h>
#include <math.h>

// ---------------------------------------------------------------------------
// Seq2Seq LSTM (S=128,B=64,I=H=O=1024,L=2,T=64) on gfx950.
// Round 12: layer-split ping-pong decoder. R8-R11 showed interval cost (~21us)
// is invariant to barrier mechanics -> the cost is structural: every block
// consumed BOTH stages' operands (512KB/block/stage) and ran two tails.
// New: blocks 0-127 own layer0 (32 perm-rows each), 128-255 own layer1.
//  - per t: L0 computes d0(t) -> flagA; L1 waits flagA, computes d1(t) ->
//    flagB; L0 at t+1 waits flagB. All-to-all flag polling (128 lanes x
//    128 private 64B lines), no master hop. Transitivity covers all deps.
//  - per block per t: ONE layer's 2 ops (K-slice 256/wave), one LDS reduce,
//    one tail, one wait. 2-nt tiles reuse each activation load twice.
//  - data path unchanged (R10/R11-proven): write-once D0[t]/H1[t], sc0sc1
//    producer stores, plain cached consumer loads, NO fences.
// Weights in registers (128 VGPR/wave, one op x 32 rows x K256 h+l).
// Encoder path unchanged.
// ---------------------------------------------------------------------------

typedef unsigned short u16;
typedef short short8 __attribute__((ext_vector_type(8)));
typedef float f32x4 __attribute__((ext_vector_type(4)));

#define MFMA_BF16 __builtin_amdgcn_mfma_f32_16x16x32_bf16

__device__ __forceinline__ u16 f2bf(float x) {
  unsigned u = __builtin_bit_cast(unsigned, x);
  unsigned r = u + 0x7fffu + ((u >> 16) & 1u);
  return (u16)(r >> 16);
}
__device__ __forceinline__ float bf2f(u16 b) {
  return __builtin_bit_cast(float, ((unsigned)b) << 16);
}
__device__ __forceinline__ int permrow(int r) {
  int gate = r >> 10, hc = r & 1023;
  return ((hc >> 2) << 4) + ((hc & 3) << 2) + gate;
}

// write-through store: commits at the device coherence point
__device__ __forceinline__ void st_sc(u16* p, u16 v) {
  unsigned vv = v;
  asm volatile("global_store_short %0, %1, off sc0 sc1" :: "v"(p), "v"(vv) : "memory");
}
// coherent (coherence-point) load/store for flag words
__device__ __forceinline__ int coh_load(const int* p) {
  int v;
  asm volatile("global_load_dword %0, %1, off sc0 sc1\n\ts_waitcnt vmcnt(0)"
               : "=v"(v) : "v"(p) : "memory");
  return v;
}
__device__ __forceinline__ void coh_store(int* p, int v) {
  asm volatile("global_store_dword %0, %1, off sc0 sc1\n\ts_waitcnt vmcnt(0)"
               :: "v"(p), "v"(v) : "memory");
}

// ---------------- prep kernels ----------------

// mode 0: plain; mode 1: transpose (1024x1024); mode 2: permute 4096 rows
__global__ void split_mat(const float* __restrict__ src, u16* __restrict__ dh,
                          u16* __restrict__ dl, int n, int mode) {
  int i = blockIdx.x * 256 + threadIdx.x;
  if (i >= n) return;
  float v = src[i];
  u16 hi = f2bf(v);
  u16 lo = f2bf(v - bf2f(hi));
  int r = i >> 10, c = i & 1023;
  int idx = i;
  if (mode == 1) idx = c * 1024 + r;
  else if (mode == 2) idx = permrow(r) * 1024 + c;
  dh[idx] = hi; dl[idx] = lo;
}

__global__ void zero_f4(float4* __restrict__ p, int n) {
  int i = blockIdx.x * 256 + threadIdx.x;
  if (i < n) p[i] = make_float4(0.f, 0.f, 0.f, 0.f);
}

__global__ void bias_perm(const float* __restrict__ in, float* __restrict__ out) {
  int i = blockIdx.x * 256 + threadIdx.x;
  if (i < 4096) out[permrow(i)] = in[i];
}

// bcomb[perm(n)] = dec_b0[n] + sum_k lin_b[k] * dec_wih0[n][k]
__global__ void bias_comb(const float* __restrict__ db0, const float* __restrict__ lb,
                          const float* __restrict__ wih, float* __restrict__ out) {
  __shared__ float red[256];
  int n = blockIdx.x;
  float s = 0.f;
  for (int k = threadIdx.x; k < 1024; k += 256) s += lb[k] * wih[(size_t)n * 1024 + k];
  red[threadIdx.x] = s;
  __syncthreads();
  for (int d = 128; d > 0; d >>= 1) {
    if (threadIdx.x < d) red[threadIdx.x] += red[threadIdx.x + d];
    __syncthreads();
  }
  if (threadIdx.x == 0) out[permrow(n)] = db0[n] + red[0];
}

// ---------- split-bf16 GEMM: C[M,N] = A[M,K] * B[N,K]^T ----------
// Block: (64*MT) M-rows x 128 N-cols; 4 waves x 2 N-tiles. gn = N/128.
// mode 0: split-bf16 C; mode 1: fp32+bias, row=(t*64+b)->out[b][t][col];
// mode 2: plain fp32 C.
template<int MT>
__global__ __launch_bounds__(256) void gemm_split(
    const u16* __restrict__ Ah, const u16* __restrict__ Al, int lda,
    const u16* __restrict__ Bh, const u16* __restrict__ Bl, int ldb,
    int K, int gn,
    u16* __restrict__ Ch, u16* __restrict__ Cl, int ldc,
    float* __restrict__ outp, const float* __restrict__ bias, int ldout, int mode) {
  int bm = blockIdx.x / gn, bn = blockIdx.x % gn;
  int l = threadIdx.x & 63, w = threadIdx.x >> 6;
  int n0 = bn * 128 + w * 32;
  int rr = l & 15, ko = (l >> 4) << 3, q = l >> 4;
  int M0 = bm * 64 * MT;
  f32x4 acc[8 * MT] = {};
  for (int kk = 0; kk < K; kk += 32) {
    short8 bh[2], bl[2];
#pragma unroll
    for (int nt = 0; nt < 2; ++nt) {
      size_t bo = (size_t)(n0 + nt * 16 + rr) * ldb + kk + ko;
      bh[nt] = *(const short8*)(Bh + bo);
      bl[nt] = *(const short8*)(Bl + bo);
    }
#pragma unroll
    for (int mt = 0; mt < 4 * MT; ++mt) {
      size_t ao = (size_t)(M0 + mt * 16 + rr) * lda + kk + ko;
      short8 ah = *(const short8*)(Ah + ao);
      short8 al = *(const short8*)(Al + ao);
#pragma unroll
      for (int nt = 0; nt < 2; ++nt) {
        f32x4 t = acc[mt * 2 + nt];
        t = MFMA_BF16(ah, bh[nt], t, 0, 0, 0);
        t = MFMA_BF16(ah, bl[nt], t, 0, 0, 0);
        t = MFMA_BF16(al, bh[nt], t, 0, 0, 0);
        acc[mt * 2 + nt] = t;
      }
    }
  }
#pragma unroll
  for (int mt = 0; mt < 4 * MT; ++mt)
#pragma unroll
    for (int nt = 0; nt < 2; ++nt)
#pragma unroll
      for (int r = 0; r < 4; ++r) {
        int row = M0 + mt * 16 + q * 4 + r;
        int col = n0 + nt * 16 + rr;
        float v = acc[mt * 2 + nt][r];
        if (mode == 0) {
          u16 hh = f2bf(v);
          Ch[(size_t)row * ldc + col] = hh;
          Cl[(size_t)row * ldc + col] = f2bf(v - bf2f(hh));
        } else if (mode == 1) {
          int t = row >> 6, b = row & 63;
          outp[(size_t)b * 65536 + t * 1024 + col] = v + bias[col];
        } else {
          outp[(size_t)row * ldout + col] = v;
        }
      }
}

// ---------------- encoder paired step kernel ----------------

struct Half {
  const u16 *Ah, *Al, *Wh, *Wl;
  const float* pre;    // fp32 [64][4096] gate slab
  const float* bias;   // permuted [4096]
  float* c;
  u16 *Hh, *Hl;
  int active;
};

__global__ __launch_bounds__(512, 1) void lstm_pair(Half hA, Half hB) {
  int j = blockIdx.x;
  Half S = (j < 128) ? hA : hB;
  if (!S.active) return;
  int sub = j & 127;
  int rowblk = ((sub & 7) << 4) | (sub >> 3);   // XCD-pinned, 0..127
  int R = rowblk << 5;                           // 32 rows
  int tid = threadIdx.x;
  int l = tid & 63, w = tid >> 6;
  int rr = l & 15, ko = (l >> 4) << 3, q = l >> 4;
  int kb = w << 7;                               // 128-wide K slice
  const u16* __restrict__ Wh = S.Wh + (size_t)(R + rr) * 1024 + kb + ko;
  const u16* __restrict__ Wl = S.Wl + (size_t)(R + rr) * 1024 + kb + ko;
  const u16* __restrict__ Ah = S.Ah + kb + ko;
  const u16* __restrict__ Al = S.Al + kb + ko;

  f32x4 acc[8] = {};
#pragma unroll
  for (int kk = 0; kk < 128; kk += 32) {
    short8 bh[2], bl[2];
#pragma unroll
    for (int nt = 0; nt < 2; ++nt) {
      bh[nt] = *(const short8*)(Wh + (size_t)(nt << 4) * 1024 + kk);
      bl[nt] = *(const short8*)(Wl + (size_t)(nt << 4) * 1024 + kk);
    }
#pragma unroll
    for (int mt = 0; mt < 4; ++mt) {
      size_t ao = (size_t)((mt << 4) + rr) * 1024 + kk;
      short8 ah = *(const short8*)(Ah + ao);
      short8 al = *(const short8*)(Al + ao);
#pragma unroll
      for (int nt = 0; nt < 2; ++nt) {
        f32x4 t = acc[mt * 2 + nt];
        t = MFMA_BF16(ah, bh[nt], t, 0, 0, 0);
        t = MFMA_BF16(ah, bl[nt], t, 0, 0, 0);
        t = MFMA_BF16(al, bh[nt], t, 0, 0, 0);
        acc[mt * 2 + nt] = t;
      }
    }
  }

  __shared__ float lds[8][64][33];
#pragma unroll
  for (int mt = 0; mt < 4; ++mt)
#pragma unroll
    for (int nt = 0; nt < 2; ++nt)
#pragma unroll
      for (int r = 0; r < 4; ++r)
        lds[w][(mt << 4) + (q << 2) + r][(nt << 4) + rr] = acc[mt * 2 + nt][r];
  __syncthreads();

  int b = tid >> 3, e = tid & 7;
  float g[4];
#pragma unroll
  for (int gt = 0; gt < 4; ++gt) {
    int c = (e << 2) + gt;
    float s = S.bias[R + c] + S.pre[(size_t)b * 4096 + R + c];
#pragma unroll
    for (int ww = 0; ww < 8; ++ww) s += lds[ww][b][c];
    g[gt] = s;
  }
  int hc = (rowblk << 3) + e;
  size_t ci = (size_t)b * 1024 + hc;
  float cold = S.c[ci];
  float is = 1.f / (1.f + expf(-g[0]));
  float fs = 1.f / (1.f + expf(-g[1]));
  float gg = tanhf(g[2]);
  float os = 1.f / (1.f + expf(-g[3]));
  float cn = fs * cold + is * gg;
  S.c[ci] = cn;
  float h = os * tanhf(cn);
  S.Hh[ci] = f2bf(h);
  S.Hl[ci] = f2bf(h - bf2f(f2bf(h)));
}

// ---------------- layer-split ping-pong decoder ----------------
// 256 blocks x 512 thr (1/CU). Blocks 0-127: layer0 (32 perm-rows each);
// 128-255: layer1. Flags: flagA[i] (d0, line i*16), flagB[i] (d1, 2048+i*16).
// Write-once D0[t]/H1[t]; plain consumer loads; no fences.

struct DecL {
  const u16 *W00h, *W00l;    // L0 op0: Wcomb  (A = h1(t-1))
  const u16 *W01h, *W01l;    // L0 op1: WhhD0  (A = h0(t-1))
  const u16 *W10h, *W10l;    // L1 op0: WihD1  (A = d0(t))
  const u16 *W11h, *W11l;    // L1 op1: WhhD1  (A = h1(t-1))
  const u16 *h0i_h, *h0i_l;  // encoder L0 final h
  const u16 *h1i_h, *h1i_l;  // encoder L1 final h
  const u16 *zh, *zl;        // zeros (t=0 L0 op0 operand)
  const float *Gd0, *dbp0, *bdec0, *dbp1;
  const float *c0, *c1;      // encoder final c (read once)
  u16 *D0h, *D0l;            // write-once [64*65536]
  u16 *H1h, *H1l;            // write-once [64*65536]
  int* bar;                  // [4096] pre-zeroed
};

__global__ __launch_bounds__(512, 1) void lstm_dec_layers(DecL D) {
  int j = blockIdx.x;
  int lay = j >> 7;                              // 0 or 1
  int sub = j & 127;
  int rowblk = ((sub & 7) << 4) | (sub >> 3);    // XCD-pinned, 0..127
  int R = rowblk << 5;                           // 32 perm rows
  int tid = threadIdx.x;
  int l = tid & 63, w = tid >> 6;
  int rr = l & 15, ko = (l >> 4) << 3, q = l >> 4;
  int opidx = w >> 2;                            // waves 0-3: op0, 4-7: op1
  int kb = (w & 3) << 8;                         // 256-wide K slice
  int* flagA = D.bar;
  int* flagB = D.bar + 2048;

  // ---- weight fragments in registers for 64 steps (one op, 32 rows) ----
  const u16* Wh_ = lay ? (opidx ? D.W11h : D.W10h) : (opidx ? D.W01h : D.W00h);
  const u16* Wl_ = lay ? (opidx ? D.W11l : D.W10l) : (opidx ? D.W01l : D.W00l);
  short8 wh[2][8], wl[2][8];
#pragma unroll
  for (int nt = 0; nt < 2; ++nt)
#pragma unroll
    for (int ki = 0; ki < 8; ++ki) {
      size_t o = (size_t)(R + (nt << 4) + rr) * 1024 + kb + (ki << 5) + ko;
      wh[nt][ki] = *(const short8*)(Wh_ + o);
      wl[nt][ki] = *(const short8*)(Wl_ + o);
    }

  // ---- tail state: every thread owns (b, e) -> one h cell ----
  int b = tid >> 3, e = tid & 7;
  int hc = (rowblk << 3) + e;
  size_t ci = (size_t)b * 1024 + hc;
  float creg = lay ? D.c1[ci] : D.c0[ci];
  float bT[4], gb0[4];
#pragma unroll
  for (int gt = 0; gt < 4; ++gt) {
    int cc = R + (e << 2) + gt;
    bT[gt] = lay ? D.dbp1[cc] : D.bdec0[cc];
    gb0[gt] = lay ? 0.f : (D.dbp0[cc] + D.Gd0[(size_t)b * 4096 + cc]);
  }

  __shared__ float lds[8][64][33];

  for (int t = 0; t < 64; ++t) {
    // ---- wait for the data this iteration needs (all-to-all flags) ----
    if (lay) {
      if (tid < 128) {
        const int* p = flagA + (tid << 4);
        while (coh_load(p) < t + 1) __builtin_amdgcn_s_sleep(4);
      }
    } else if (t > 0) {
      if (tid < 128) {
        const int* p = flagB + (tid << 4);
        while (coh_load(p) < t) __builtin_amdgcn_s_sleep(4);
      }
    }
    __syncthreads();

    // ---- operand selection (all write-once slabs) ----
    const u16 *Aph, *Apl;
    if (!lay) {
      if (opidx == 0) {
        Aph = t ? D.H1h + (size_t)(t - 1) * 65536 : D.zh;
        Apl = t ? D.H1l + (size_t)(t - 1) * 65536 : D.zl;
      } else {
        Aph = t ? D.D0h + (size_t)(t - 1) * 65536 : D.h0i_h;
        Apl = t ? D.D0l + (size_t)(t - 1) * 65536 : D.h0i_l;
      }
    } else {
      if (opidx == 0) {
        Aph = D.D0h + (size_t)t * 65536;
        Apl = D.D0l + (size_t)t * 65536;
      } else {
        Aph = t ? D.H1h + (size_t)(t - 1) * 65536 : D.h1i_h;
        Apl = t ? D.H1l + (size_t)(t - 1) * 65536 : D.h1i_l;
      }
    }
    const u16* __restrict__ Ah_ = Aph + kb + ko;
    const u16* __restrict__ Al_ = Apl + kb + ko;

    f32x4 acc[8] = {};
#pragma unroll
    for (int ki = 0; ki < 8; ++ki) {
#pragma unroll
      for (int mt = 0; mt < 4; ++mt) {
        size_t ao = (size_t)((mt << 4) + rr) * 1024 + (ki << 5);
        short8 ah = *(const short8*)(Ah_ + ao);
        short8 al = *(const short8*)(Al_ + ao);
#pragma unroll
        for (int nt = 0; nt < 2; ++nt) {
          f32x4 tacc = acc[mt * 2 + nt];
          tacc = MFMA_BF16(ah, wh[nt][ki], tacc, 0, 0, 0);
          tacc = MFMA_BF16(ah, wl[nt][ki], tacc, 0, 0, 0);
          tacc = MFMA_BF16(al, wh[nt][ki], tacc, 0, 0, 0);
          acc[mt * 2 + nt] = tacc;
        }
      }
    }
#pragma unroll
    for (int mt = 0; mt < 4; ++mt)
#pragma unroll
      for (int nt = 0; nt < 2; ++nt)
#pragma unroll
        for (int r = 0; r < 4; ++r)
          lds[w][(mt << 4) + (q << 2) + r][(nt << 4) + rr] = acc[mt * 2 + nt][r];
    __syncthreads();

    // ---- tail: all 512 threads, one (b, hc) cell each ----
    float g[4];
#pragma unroll
    for (int gt = 0; gt < 4; ++gt) {
      int c = (e << 2) + gt;
      float s = (!lay && t == 0) ? gb0[gt] : bT[gt];
#pragma unroll
      for (int ww = 0; ww < 8; ++ww) s += lds[ww][b][c];
      g[gt] = s;
    }
    float is = 1.f / (1.f + expf(-g[0]));
    float fs = 1.f / (1.f + expf(-g[1]));
    float gg = tanhf(g[2]);
    float os = 1.f / (1.f + expf(-g[3]));
    float cn = fs * creg + is * gg;
    creg = cn;
    float h = os * tanhf(cn);
    u16 hh = f2bf(h), hl = f2bf(h - bf2f(hh));
    size_t oidx = (size_t)t * 65536 + ci;
    if (!lay) { st_sc(D.D0h + oidx, hh); st_sc(D.D0l + oidx, hl); }
    else      { st_sc(D.H1h + oidx, hh); st_sc(D.H1l + oidx, hl); }
    __syncthreads();   // drain all waves' stores + LDS reuse guard
    if (tid == 0) coh_store((lay ? flagB : flagA) + (sub << 4), t + 1);
  }
}

// ---------------- host ----------------

extern "C" void kernel_launch(void* const* d_in, const int* in_sizes, int n_in,
                              void* d_out, int out_size, void* d_ws, size_t ws_size,
                              hipStream_t stream) {
  (void)in_sizes; (void)n_in; (void)out_size; (void)ws_size;
  const float* input_seq = (const float*)d_in[0];
  const float* enc_wih   = (const float*)d_in[1];
  const float* enc_whh   = (const float*)d_in[2];
  const float* enc_b     = (const float*)d_in[3];
  const float* dec_wih   = (const float*)d_in[4];
  const float* dec_whh   = (const float*)d_in[5];
  const float* dec_b     = (const float*)d_in[6];
  const float* lin_w     = (const float*)d_in[7];
  const float* lin_b     = (const float*)d_in[8];
  float* out = (float*)d_out;

  const size_t WE = 4096ull * 1024;
  const size_t HB = 64ull * 1024;
  char* ws = (char*)d_ws;
  size_t off = 0;
  auto alloc16 = [&](size_t elems) {
    u16* p = (u16*)(ws + off);
    off = (off + elems * 2 + 255) & ~(size_t)255;
    return p;
  };
  auto allocf = [&](size_t elems) {
    float* p = (float*)(ws + off);
    off = (off + elems * 4 + 255) & ~(size_t)255;
    return p;
  };

  // weights (permuted rows) split hi/lo: 9 pairs x 16 MB = 144 MB
  u16 *WihE0h = alloc16(WE), *WihE0l = alloc16(WE);
  u16 *WhhE0h = alloc16(WE), *WhhE0l = alloc16(WE);
  u16 *WihE1h = alloc16(WE), *WihE1l = alloc16(WE);
  u16 *WhhE1h = alloc16(WE), *WhhE1l = alloc16(WE);
  u16 *WihD0h = alloc16(WE), *WihD0l = alloc16(WE);
  u16 *WhhD0h = alloc16(WE), *WhhD0l = alloc16(WE);
  u16 *WihD1h = alloc16(WE), *WihD1l = alloc16(WE);
  u16 *WhhD1h = alloc16(WE), *WhhD1l = alloc16(WE);
  u16 *Wcombh = alloc16(WE), *Wcombl = alloc16(WE);
  u16 *WLh  = alloc16(1024 * 1024), *WLl  = alloc16(1024 * 1024);
  u16 *WLTh = alloc16(1024 * 1024), *WLTl = alloc16(1024 * 1024);
  u16 *XCh = alloc16(16 * HB), *XCl = alloc16(16 * HB);     // x chunk
  u16 *XLh = alloc16(HB), *XLl = alloc16(HB);               // x_last
  u16 *H0ch = alloc16(17 * HB), *H0cl = alloc16(17 * HB);   // h0 ring
  u16 *H1h = alloc16(64 * HB), *H1l = alloc16(64 * HB);     // dec h1 write-once
  u16 *D0h = alloc16(64 * HB), *D0l = alloc16(64 * HB);     // dec d0 write-once
  // zero region
  size_t zbeg = off;
  u16 *zh = alloc16(HB), *zl = alloc16(HB);
  float *c0 = allocf(HB), *c1 = allocf(HB);
  int *barbuf = (int*)(ws + off);
  off = (off + 4096 * sizeof(int) + 255) & ~(size_t)255;
  size_t zend = off;
  // ping-pong h slots (encoder L1)
  u16 *e1h = alloc16(2 * HB), *e1l = alloc16(2 * HB);
  // gate buffers (fp32)
  float *G0 = allocf(1024ull * 4096);   // 16 MB
  float *G1 = allocf(1024ull * 4096);   // 16 MB
  float *Gd0 = allocf(64 * 4096);
  // biases
  float *ebp0 = allocf(4096), *ebp1 = allocf(4096);
  float *dbp0 = allocf(4096), *dbp1 = allocf(4096);
  float *bdec0 = allocf(4096);
  // total ~229 MB

  // 1) zeros (incl. flag lines)
  {
    int n4 = (int)((zend - zbeg) / 16);
    zero_f4<<<dim3((n4 + 255) / 256), dim3(256), 0, stream>>>((float4*)(ws + zbeg), n4);
  }
  // 2) splits
  auto split = [&](const float* src, u16* dh, u16* dl, int n, int mode) {
    split_mat<<<dim3((n + 255) / 256), dim3(256), 0, stream>>>(src, dh, dl, n, mode);
  };
  split(enc_wih,        WihE0h, WihE0l, (int)WE, 2);
  split(enc_whh,        WhhE0h, WhhE0l, (int)WE, 2);
  split(enc_wih + WE,   WihE1h, WihE1l, (int)WE, 2);
  split(enc_whh + WE,   WhhE1h, WhhE1l, (int)WE, 2);
  split(dec_wih,        WihD0h, WihD0l, (int)WE, 2);
  split(dec_whh,        WhhD0h, WhhD0l, (int)WE, 2);
  split(dec_wih + WE,   WihD1h, WihD1l, (int)WE, 2);
  split(dec_whh + WE,   WhhD1h, WhhD1l, (int)WE, 2);
  split(lin_w, WLh,  WLl,  1024 * 1024, 0);
  split(lin_w, WLTh, WLTl, 1024 * 1024, 1);
  split(input_seq + 127ull * HB, XLh, XLl, (int)HB, 0);
  // 3) biases
  bias_perm<<<dim3(16), dim3(256), 0, stream>>>(enc_b,        ebp0);
  bias_perm<<<dim3(16), dim3(256), 0, stream>>>(enc_b + 4096, ebp1);
  bias_perm<<<dim3(16), dim3(256), 0, stream>>>(dec_b,        dbp0);
  bias_perm<<<dim3(16), dim3(256), 0, stream>>>(dec_b + 4096, dbp1);
  bias_comb<<<dim3(4096), dim3(256), 0, stream>>>(dec_b, lin_b, dec_wih, bdec0);
  // 4) Wcomb = WihD0(perm) @ lin_w : M=4096,N=1024 -> 32x8 blocks
  gemm_split<2><<<dim3(32 * 8), dim3(256), 0, stream>>>(
      WihD0h, WihD0l, 1024, WLTh, WLTl, 1024, 1024, 8,
      Wcombh, Wcombl, 1024, nullptr, nullptr, 0, 0);
  // 4b) Gd0 = x_last @ WihD0^T : M=64,N=4096 -> 1x32 blocks
  gemm_split<1><<<dim3(32), dim3(256), 0, stream>>>(
      XLh, XLl, 1024, WihD0h, WihD0l, 1024, 1024, 32,
      nullptr, nullptr, 0, Gd0, nullptr, 4096, 2);

  // 5) encoder: chunk ch: G0 gemm; paired steps L0(ch)+L1(ch-1); G1 gemm.
  for (int ch = 0; ch < 8; ++ch) {
    split(input_seq + (size_t)ch * 16 * HB, XCh, XCl, (int)(16 * HB), 0);
    gemm_split<2><<<dim3(8 * 32), dim3(256), 0, stream>>>(
        XCh, XCl, 1024, WihE0h, WihE0l, 1024, 1024, 32,
        nullptr, nullptr, 0, G0, nullptr, 4096, 2);
    for (int lt = 0; lt < 16; ++lt) {
      int t0 = ch * 16 + lt;               // L0 step index
      int t1 = (ch - 1) * 16 + lt;         // L1 step index (lagged)
      Half A;
      A.Ah = (t0 == 0) ? zh : (lt == 0 ? H0ch + 16ull * HB : H0ch + (size_t)lt * HB);
      A.Al = (t0 == 0) ? zl : (lt == 0 ? H0cl + 16ull * HB : H0cl + (size_t)lt * HB);
      A.Wh = WhhE0h; A.Wl = WhhE0l;
      A.pre = G0 + (size_t)lt * 64 * 4096;
      A.bias = ebp0; A.c = c0;
      A.Hh = H0ch + (size_t)(lt + 1) * HB; A.Hl = H0cl + (size_t)(lt + 1) * HB;
      A.active = 1;
      Half B;
      B.Ah = (t1 == 0) ? zh : e1h + (size_t)((t1 - 1) & 1) * HB;
      B.Al = (t1 == 0) ? zl : e1l + (size_t)((t1 - 1) & 1) * HB;
      B.Wh = WhhE1h; B.Wl = WhhE1l;
      B.pre = G1 + (size_t)lt * 64 * 4096;
      B.bias = ebp1; B.c = c1;
      B.Hh = e1h + (size_t)((t1 >= 0 ? t1 : 0) & 1) * HB;
      B.Hl = e1l + (size_t)((t1 >= 0 ? t1 : 0) & 1) * HB;
      B.active = (ch >= 1) ? 1 : 0;
      lstm_pair<<<dim3(256), dim3(512), 0, stream>>>(A, B);
    }
    gemm_split<2><<<dim3(8 * 32), dim3(256), 0, stream>>>(
        H0ch + HB, H0cl + HB, 1024, WihE1h, WihE1l, 1024, 1024, 32,
        nullptr, nullptr, 0, G1, nullptr, 4096, 2);
  }
  // drain: L1 steps for ch=7 (t1 = 112..127)
  for (int lt = 0; lt < 16; ++lt) {
    int t1 = 112 + lt;
    Half A; A.active = 0;
    A.Ah = zh; A.Al = zl; A.Wh = WhhE0h; A.Wl = WhhE0l;
    A.pre = G0; A.bias = ebp0; A.c = c0; A.Hh = H0ch; A.Hl = H0cl;
    Half B;
    B.Ah = e1h + (size_t)((t1 - 1) & 1) * HB;
    B.Al = e1l + (size_t)((t1 - 1) & 1) * HB;
    B.Wh = WhhE1h; B.Wl = WhhE1l;
    B.pre = G1 + (size_t)lt * 64 * 4096;
    B.bias = ebp1; B.c = c1;
    B.Hh = e1h + (size_t)(t1 & 1) * HB;
    B.Hl = e1l + (size_t)(t1 & 1) * HB;
    B.active = 1;
    lstm_pair<<<dim3(256), dim3(512), 0, stream>>>(A, B);
  }

  // 6) decoder: ONE persistent kernel, layer-split ping-pong, 64 steps
  {
    DecL P;
    P.W00h = Wcombh; P.W00l = Wcombl;
    P.W01h = WhhD0h; P.W01l = WhhD0l;
    P.W10h = WihD1h; P.W10l = WihD1l;
    P.W11h = WhhD1h; P.W11l = WhhD1l;
    P.h0i_h = H0ch + 16ull * HB; P.h0i_l = H0cl + 16ull * HB;
    P.h1i_h = e1h + HB; P.h1i_l = e1l + HB;
    P.zh = zh; P.zl = zl;
    P.Gd0 = Gd0; P.dbp0 = dbp0; P.bdec0 = bdec0; P.dbp1 = dbp1;
    P.c0 = c0; P.c1 = c1;
    P.D0h = D0h; P.D0l = D0l;
    P.H1h = H1h; P.H1l = H1l;
    P.bar = barbuf;
    lstm_dec_layers<<<dim3(256), dim3(512), 0, stream>>>(P);
  }

  // 7) y[b][t][o] = H1[t*64+b][:] . lin_w[o][:] + lin_b[o] : M=4096,N=1024
  gemm_split<2><<<dim3(32 * 8), dim3(256), 0, stream>>>(
      H1h, H1l, 1024, WLh, WLl, 1024, 1024, 8,
      nullptr, nullptr, 0, out, lin_b, 1024, 1);
}

// Round 7
// 6127.048 us; speedup vs baseline: 1.0612x; 1.0513x over previous
//
#include <hip/hip_runtime.h>
#include <math.h>

// ---------------------------------------------------------------------------
// Seq2Seq LSTM (S=128,B=64,I=H=O=1024,L=2,T=64) on gfx950.
// Round 13: attack the ~20us hop constant, identified (R7-R12 invariance) as
// the consumer's 512KB operand load running at ~25 GB/s/CU -- latency-bound
// because 128 weight-pinned VGPRs leave the compiler ~5 outstanding loads.
// Changes (decoder only, R12 layer-split base):
//  1. Explicit 2-batch register pipeline in the MFMA loop: 8x1KB loads of
//     k-batch ki+1 issued before MFMAs of batch ki (fully unrolled, static
//     indices). ~3-4x effective load concurrency.
//  2. Own-op-first scheduling: op1's operand is the block's OWN layer's
//     t-1 output; its completeness is implied by STALE flags (set one hop
//     ago) -> near-zero wait. Only op0 (cross-layer) waits the FRESH flag.
//     Per-wave polling, no entry barrier: own-op MFMA of layer X overlaps
//     the other layer's stage on otherwise-idle CUs.
//     Visibility proof: L0@t own-op needs d0(t-1) [all L0 peers]; peer k set
//     flagA[k]=t AFTER its d0(t-1) sc0sc1 stores drained -> wait flagA>=t.
//     L1@t own-op needs h1(t-1): peers set flagB[k]=t after t-1 -> flagB>=t.
//     Cross: L0@t waits flagB>=t (L1 done t-1 -> h1(t-1) full);
//            L1@t waits flagA>=t+1 (L0 done t -> d0(t) full).
// Data path unchanged (R10-R12-proven): write-once D0[t]/H1[t], sc0sc1
// producer stores, plain cached consumer loads, no fences. Encoder unchanged.
// ---------------------------------------------------------------------------

typedef unsigned short u16;
typedef short short8 __attribute__((ext_vector_type(8)));
typedef float f32x4 __attribute__((ext_vector_type(4)));

#define MFMA_BF16 __builtin_amdgcn_mfma_f32_16x16x32_bf16

__device__ __forceinline__ u16 f2bf(float x) {
  unsigned u = __builtin_bit_cast(unsigned, x);
  unsigned r = u + 0x7fffu + ((u >> 16) & 1u);
  return (u16)(r >> 16);
}
__device__ __forceinline__ float bf2f(u16 b) {
  return __builtin_bit_cast(float, ((unsigned)b) << 16);
}
__device__ __forceinline__ int permrow(int r) {
  int gate = r >> 10, hc = r & 1023;
  return ((hc >> 2) << 4) + ((hc & 3) << 2) + gate;
}

// write-through store: commits at the device coherence point
__device__ __forceinline__ void st_sc(u16* p, u16 v) {
  unsigned vv = v;
  asm volatile("global_store_short %0, %1, off sc0 sc1" :: "v"(p), "v"(vv) : "memory");
}
// coherent (coherence-point) load/store for flag words
__device__ __forceinline__ int coh_load(const int* p) {
  int v;
  asm volatile("global_load_dword %0, %1, off sc0 sc1\n\ts_waitcnt vmcnt(0)"
               : "=v"(v) : "v"(p) : "memory");
  return v;
}
__device__ __forceinline__ void coh_store(int* p, int v) {
  asm volatile("global_store_dword %0, %1, off sc0 sc1\n\ts_waitcnt vmcnt(0)"
               :: "v"(p), "v"(v) : "memory");
}

// wave-wide flag wait: lane l checks flags[l] and flags[l+64] (128 flags)
__device__ __forceinline__ void wave_wait(const int* fl, int need, int l) {
  const int* p1 = fl + (l << 4);
  while (coh_load(p1) < need) __builtin_amdgcn_s_sleep(1);
  const int* p2 = fl + ((l + 64) << 4);
  while (coh_load(p2) < need) __builtin_amdgcn_s_sleep(1);
}

// ---------------- prep kernels ----------------

// mode 0: plain; mode 1: transpose (1024x1024); mode 2: permute 4096 rows
__global__ void split_mat(const float* __restrict__ src, u16* __restrict__ dh,
                          u16* __restrict__ dl, int n, int mode) {
  int i = blockIdx.x * 256 + threadIdx.x;
  if (i >= n) return;
  float v = src[i];
  u16 hi = f2bf(v);
  u16 lo = f2bf(v - bf2f(hi));
  int r = i >> 10, c = i & 1023;
  int idx = i;
  if (mode == 1) idx = c * 1024 + r;
  else if (mode == 2) idx = permrow(r) * 1024 + c;
  dh[idx] = hi; dl[idx] = lo;
}

__global__ void zero_f4(float4* __restrict__ p, int n) {
  int i = blockIdx.x * 256 + threadIdx.x;
  if (i < n) p[i] = make_float4(0.f, 0.f, 0.f, 0.f);
}

__global__ void bias_perm(const float* __restrict__ in, float* __restrict__ out) {
  int i = blockIdx.x * 256 + threadIdx.x;
  if (i < 4096) out[permrow(i)] = in[i];
}

// bcomb[perm(n)] = dec_b0[n] + sum_k lin_b[k] * dec_wih0[n][k]
__global__ void bias_comb(const float* __restrict__ db0, const float* __restrict__ lb,
                          const float* __restrict__ wih, float* __restrict__ out) {
  __shared__ float red[256];
  int n = blockIdx.x;
  float s = 0.f;
  for (int k = threadIdx.x; k < 1024; k += 256) s += lb[k] * wih[(size_t)n * 1024 + k];
  red[threadIdx.x] = s;
  __syncthreads();
  for (int d = 128; d > 0; d >>= 1) {
    if (threadIdx.x < d) red[threadIdx.x] += red[threadIdx.x + d];
    __syncthreads();
  }
  if (threadIdx.x == 0) out[permrow(n)] = db0[n] + red[0];
}

// ---------- split-bf16 GEMM: C[M,N] = A[M,K] * B[N,K]^T ----------
template<int MT>
__global__ __launch_bounds__(256) void gemm_split(
    const u16* __restrict__ Ah, const u16* __restrict__ Al, int lda,
    const u16* __restrict__ Bh, const u16* __restrict__ Bl, int ldb,
    int K, int gn,
    u16* __restrict__ Ch, u16* __restrict__ Cl, int ldc,
    float* __restrict__ outp, const float* __restrict__ bias, int ldout, int mode) {
  int bm = blockIdx.x / gn, bn = blockIdx.x % gn;
  int l = threadIdx.x & 63, w = threadIdx.x >> 6;
  int n0 = bn * 128 + w * 32;
  int rr = l & 15, ko = (l >> 4) << 3, q = l >> 4;
  int M0 = bm * 64 * MT;
  f32x4 acc[8 * MT] = {};
  for (int kk = 0; kk < K; kk += 32) {
    short8 bh[2], bl[2];
#pragma unroll
    for (int nt = 0; nt < 2; ++nt) {
      size_t bo = (size_t)(n0 + nt * 16 + rr) * ldb + kk + ko;
      bh[nt] = *(const short8*)(Bh + bo);
      bl[nt] = *(const short8*)(Bl + bo);
    }
#pragma unroll
    for (int mt = 0; mt < 4 * MT; ++mt) {
      size_t ao = (size_t)(M0 + mt * 16 + rr) * lda + kk + ko;
      short8 ah = *(const short8*)(Ah + ao);
      short8 al = *(const short8*)(Al + ao);
#pragma unroll
      for (int nt = 0; nt < 2; ++nt) {
        f32x4 t = acc[mt * 2 + nt];
        t = MFMA_BF16(ah, bh[nt], t, 0, 0, 0);
        t = MFMA_BF16(ah, bl[nt], t, 0, 0, 0);
        t = MFMA_BF16(al, bh[nt], t, 0, 0, 0);
        acc[mt * 2 + nt] = t;
      }
    }
  }
#pragma unroll
  for (int mt = 0; mt < 4 * MT; ++mt)
#pragma unroll
    for (int nt = 0; nt < 2; ++nt)
#pragma unroll
      for (int r = 0; r < 4; ++r) {
        int row = M0 + mt * 16 + q * 4 + r;
        int col = n0 + nt * 16 + rr;
        float v = acc[mt * 2 + nt][r];
        if (mode == 0) {
          u16 hh = f2bf(v);
          Ch[(size_t)row * ldc + col] = hh;
          Cl[(size_t)row * ldc + col] = f2bf(v - bf2f(hh));
        } else if (mode == 1) {
          int t = row >> 6, b = row & 63;
          outp[(size_t)b * 65536 + t * 1024 + col] = v + bias[col];
        } else {
          outp[(size_t)row * ldout + col] = v;
        }
      }
}

// ---------------- encoder paired step kernel ----------------

struct Half {
  const u16 *Ah, *Al, *Wh, *Wl;
  const float* pre;    // fp32 [64][4096] gate slab
  const float* bias;   // permuted [4096]
  float* c;
  u16 *Hh, *Hl;
  int active;
};

__global__ __launch_bounds__(512, 1) void lstm_pair(Half hA, Half hB) {
  int j = blockIdx.x;
  Half S = (j < 128) ? hA : hB;
  if (!S.active) return;
  int sub = j & 127;
  int rowblk = ((sub & 7) << 4) | (sub >> 3);   // XCD-pinned, 0..127
  int R = rowblk << 5;                           // 32 rows
  int tid = threadIdx.x;
  int l = tid & 63, w = tid >> 6;
  int rr = l & 15, ko = (l >> 4) << 3, q = l >> 4;
  int kb = w << 7;                               // 128-wide K slice
  const u16* __restrict__ Wh = S.Wh + (size_t)(R + rr) * 1024 + kb + ko;
  const u16* __restrict__ Wl = S.Wl + (size_t)(R + rr) * 1024 + kb + ko;
  const u16* __restrict__ Ah = S.Ah + kb + ko;
  const u16* __restrict__ Al = S.Al + kb + ko;

  f32x4 acc[8] = {};
#pragma unroll
  for (int kk = 0; kk < 128; kk += 32) {
    short8 bh[2], bl[2];
#pragma unroll
    for (int nt = 0; nt < 2; ++nt) {
      bh[nt] = *(const short8*)(Wh + (size_t)(nt << 4) * 1024 + kk);
      bl[nt] = *(const short8*)(Wl + (size_t)(nt << 4) * 1024 + kk);
    }
#pragma unroll
    for (int mt = 0; mt < 4; ++mt) {
      size_t ao = (size_t)((mt << 4) + rr) * 1024 + kk;
      short8 ah = *(const short8*)(Ah + ao);
      short8 al = *(const short8*)(Al + ao);
#pragma unroll
      for (int nt = 0; nt < 2; ++nt) {
        f32x4 t = acc[mt * 2 + nt];
        t = MFMA_BF16(ah, bh[nt], t, 0, 0, 0);
        t = MFMA_BF16(ah, bl[nt], t, 0, 0, 0);
        t = MFMA_BF16(al, bh[nt], t, 0, 0, 0);
        acc[mt * 2 + nt] = t;
      }
    }
  }

  __shared__ float lds[8][64][33];
#pragma unroll
  for (int mt = 0; mt < 4; ++mt)
#pragma unroll
    for (int nt = 0; nt < 2; ++nt)
#pragma unroll
      for (int r = 0; r < 4; ++r)
        lds[w][(mt << 4) + (q << 2) + r][(nt << 4) + rr] = acc[mt * 2 + nt][r];
  __syncthreads();

  int b = tid >> 3, e = tid & 7;
  float g[4];
#pragma unroll
  for (int gt = 0; gt < 4; ++gt) {
    int c = (e << 2) + gt;
    float s = S.bias[R + c] + S.pre[(size_t)b * 4096 + R + c];
#pragma unroll
    for (int ww = 0; ww < 8; ++ww) s += lds[ww][b][c];
    g[gt] = s;
  }
  int hc = (rowblk << 3) + e;
  size_t ci = (size_t)b * 1024 + hc;
  float cold = S.c[ci];
  float is = 1.f / (1.f + expf(-g[0]));
  float fs = 1.f / (1.f + expf(-g[1]));
  float gg = tanhf(g[2]);
  float os = 1.f / (1.f + expf(-g[3]));
  float cn = fs * cold + is * gg;
  S.c[ci] = cn;
  float h = os * tanhf(cn);
  S.Hh[ci] = f2bf(h);
  S.Hl[ci] = f2bf(h - bf2f(f2bf(h)));
}

// ---------------- layer-split ping-pong decoder ----------------
// 256 blocks x 512 thr (1/CU). Blocks 0-127: layer0 (32 perm-rows each);
// 128-255: layer1. Flags: flagA[i] (d0, line i*16), flagB[i] (d1, 2048+i*16).
// Write-once D0[t]/H1[t]; plain consumer loads; no fences.

struct DecL {
  const u16 *W00h, *W00l;    // L0 op0: Wcomb  (A = h1(t-1))   [cross]
  const u16 *W01h, *W01l;    // L0 op1: WhhD0  (A = d0(t-1))   [own]
  const u16 *W10h, *W10l;    // L1 op0: WihD1  (A = d0(t))     [cross]
  const u16 *W11h, *W11l;    // L1 op1: WhhD1  (A = h1(t-1))   [own]
  const u16 *h0i_h, *h0i_l;  // encoder L0 final h
  const u16 *h1i_h, *h1i_l;  // encoder L1 final h
  const u16 *zh, *zl;        // zeros (t=0 L0 op0 operand)
  const float *Gd0, *dbp0, *bdec0, *dbp1;
  const float *c0, *c1;      // encoder final c (read once)
  u16 *D0h, *D0l;            // write-once [64*65536]
  u16 *H1h, *H1l;            // write-once [64*65536]
  int* bar;                  // [4096] pre-zeroed
};

// load batch KI (4 m-tiles x (ah,al)) and MFMA batch KI against weights
#define LOADK(AH, AL, KI)                                              \
  _Pragma("unroll")                                                    \
  for (int mt = 0; mt < 4; ++mt) {                                     \
    size_t ao = (size_t)((mt << 4) + rr) * 1024 + ((KI) << 5);         \
    AH[mt] = *(const short8*)(Ah_ + ao);                               \
    AL[mt] = *(const short8*)(Al_ + ao);                               \
  }
#define MFMAK(AH, AL, KI)                                              \
  _Pragma("unroll")                                                    \
  for (int mt = 0; mt < 4; ++mt) {                                     \
    _Pragma("unroll")                                                  \
    for (int nt = 0; nt < 2; ++nt) {                                   \
      f32x4 tacc = acc[mt * 2 + nt];                                   \
      tacc = MFMA_BF16(AH[mt], wh[nt][KI], tacc, 0, 0, 0);             \
      tacc = MFMA_BF16(AH[mt], wl[nt][KI], tacc, 0, 0, 0);             \
      tacc = MFMA_BF16(AL[mt], wh[nt][KI], tacc, 0, 0, 0);             \
      acc[mt * 2 + nt] = tacc;                                         \
    }                                                                  \
  }

__global__ __launch_bounds__(512, 1) void lstm_dec_layers(DecL D) {
  int j = blockIdx.x;
  int lay = j >> 7;                              // 0 or 1
  int sub = j & 127;
  int rowblk = ((sub & 7) << 4) | (sub >> 3);    // XCD-pinned, 0..127
  int R = rowblk << 5;                           // 32 perm rows
  int tid = threadIdx.x;
  int l = tid & 63, w = tid >> 6;
  int rr = l & 15, ko = (l >> 4) << 3, q = l >> 4;
  int opidx = w >> 2;                            // waves 0-3: op0(cross), 4-7: op1(own)
  int kb = (w & 3) << 8;                         // 256-wide K slice
  int* flagA = D.bar;
  int* flagB = D.bar + 2048;

  // ---- weight fragments in registers for 64 steps (one op, 32 rows) ----
  const u16* Wh_ = lay ? (opidx ? D.W11h : D.W10h) : (opidx ? D.W01h : D.W00h);
  const u16* Wl_ = lay ? (opidx ? D.W11l : D.W10l) : (opidx ? D.W01l : D.W00l);
  short8 wh[2][8], wl[2][8];
#pragma unroll
  for (int nt = 0; nt < 2; ++nt)
#pragma unroll
    for (int ki = 0; ki < 8; ++ki) {
      size_t o = (size_t)(R + (nt << 4) + rr) * 1024 + kb + (ki << 5) + ko;
      wh[nt][ki] = *(const short8*)(Wh_ + o);
      wl[nt][ki] = *(const short8*)(Wl_ + o);
    }

  // ---- tail state: every thread owns (b, e) -> one h cell ----
  int b = tid >> 3, e = tid & 7;
  int hc = (rowblk << 3) + e;
  size_t ci = (size_t)b * 1024 + hc;
  float creg = lay ? D.c1[ci] : D.c0[ci];
  float bT[4], gb0[4];
#pragma unroll
  for (int gt = 0; gt < 4; ++gt) {
    int cc = R + (e << 2) + gt;
    bT[gt] = lay ? D.dbp1[cc] : D.bdec0[cc];
    gb0[gt] = lay ? 0.f : (D.dbp0[cc] + D.Gd0[(size_t)b * 4096 + cc]);
  }

  __shared__ float lds[8][64][33];

  for (int t = 0; t < 64; ++t) {
    // ---- per-wave dependency wait ----
    if (opidx == 1) {
      // own-layer operand (peers' t-1 output): stale flag, near-instant
      if (t > 0) wave_wait(lay ? flagB : flagA, t, l);
    } else {
      // cross-layer operand: fresh flag
      if (lay)            wave_wait(flagA, t + 1, l);
      else if (t > 0)     wave_wait(flagB, t, l);
    }

    // ---- operand selection (all write-once slabs) ----
    const u16 *Aph, *Apl;
    if (!lay) {
      if (opidx == 0) {
        Aph = t ? D.H1h + (size_t)(t - 1) * 65536 : D.zh;
        Apl = t ? D.H1l + (size_t)(t - 1) * 65536 : D.zl;
      } else {
        Aph = t ? D.D0h + (size_t)(t - 1) * 65536 : D.h0i_h;
        Apl = t ? D.D0l + (size_t)(t - 1) * 65536 : D.h0i_l;
      }
    } else {
      if (opidx == 0) {
        Aph = D.D0h + (size_t)t * 65536;
        Apl = D.D0l + (size_t)t * 65536;
      } else {
        Aph = t ? D.H1h + (size_t)(t - 1) * 65536 : D.h1i_h;
        Apl = t ? D.H1l + (size_t)(t - 1) * 65536 : D.h1i_l;
      }
    }
    const u16* __restrict__ Ah_ = Aph + kb + ko;
    const u16* __restrict__ Al_ = Apl + kb + ko;

    // ---- pipelined load + MFMA (1-2 batches of 8x1KB in flight) ----
    f32x4 acc[8] = {};
    {
      short8 xah[4], xal[4], yah[4], yal[4];
      LOADK(xah, xal, 0)
      LOADK(yah, yal, 1)
      MFMAK(xah, xal, 0)
      LOADK(xah, xal, 2)
      MFMAK(yah, yal, 1)
      LOADK(yah, yal, 3)
      MFMAK(xah, xal, 2)
      LOADK(xah, xal, 4)
      MFMAK(yah, yal, 3)
      LOADK(yah, yal, 5)
      MFMAK(xah, xal, 4)
      LOADK(xah, xal, 6)
      MFMAK(yah, yal, 5)
      LOADK(yah, yal, 7)
      MFMAK(xah, xal, 6)
      MFMAK(yah, yal, 7)
    }
#pragma unroll
    for (int mt = 0; mt < 4; ++mt)
#pragma unroll
      for (int nt = 0; nt < 2; ++nt)
#pragma unroll
        for (int r = 0; r < 4; ++r)
          lds[w][(mt << 4) + (q << 2) + r][(nt << 4) + rr] = acc[mt * 2 + nt][r];
    __syncthreads();

    // ---- tail: all 512 threads, one (b, hc) cell each ----
    float g[4];
#pragma unroll
    for (int gt = 0; gt < 4; ++gt) {
      int c = (e << 2) + gt;
      float s = (!lay && t == 0) ? gb0[gt] : bT[gt];
#pragma unroll
      for (int ww = 0; ww < 8; ++ww) s += lds[ww][b][c];
      g[gt] = s;
    }
    float is = 1.f / (1.f + expf(-g[0]));
    float fs = 1.f / (1.f + expf(-g[1]));
    float gg = tanhf(g[2]);
    float os = 1.f / (1.f + expf(-g[3]));
    float cn = fs * creg + is * gg;
    creg = cn;
    float h = os * tanhf(cn);
    u16 hh = f2bf(h), hl = f2bf(h - bf2f(hh));
    size_t oidx = (size_t)t * 65536 + ci;
    if (!lay) { st_sc(D.D0h + oidx, hh); st_sc(D.D0l + oidx, hl); }
    else      { st_sc(D.H1h + oidx, hh); st_sc(D.H1l + oidx, hl); }
    __syncthreads();   // drain all waves' stores + LDS reuse guard
    if (tid == 0) coh_store((lay ? flagB : flagA) + (sub << 4), t + 1);
  }
}

// ---------------- host ----------------

extern "C" void kernel_launch(void* const* d_in, const int* in_sizes, int n_in,
                              void* d_out, int out_size, void* d_ws, size_t ws_size,
                              hipStream_t stream) {
  (void)in_sizes; (void)n_in; (void)out_size; (void)ws_size;
  const float* input_seq = (const float*)d_in[0];
  const float* enc_wih   = (const float*)d_in[1];
  const float* enc_whh   = (const float*)d_in[2];
  const float* enc_b     = (const float*)d_in[3];
  const float* dec_wih   = (const float*)d_in[4];
  const float* dec_whh   = (const float*)d_in[5];
  const float* dec_b     = (const float*)d_in[6];
  const float* lin_w     = (const float*)d_in[7];
  const float* lin_b     = (const float*)d_in[8];
  float* out = (float*)d_out;

  const size_t WE = 4096ull * 1024;
  const size_t HB = 64ull * 1024;
  char* ws = (char*)d_ws;
  size_t off = 0;
  auto alloc16 = [&](size_t elems) {
    u16* p = (u16*)(ws + off);
    off = (off + elems * 2 + 255) & ~(size_t)255;
    return p;
  };
  auto allocf = [&](size_t elems) {
    float* p = (float*)(ws + off);
    off = (off + elems * 4 + 255) & ~(size_t)255;
    return p;
  };

  // weights (permuted rows) split hi/lo: 9 pairs x 16 MB = 144 MB
  u16 *WihE0h = alloc16(WE), *WihE0l = alloc16(WE);
  u16 *WhhE0h = alloc16(WE), *WhhE0l = alloc16(WE);
  u16 *WihE1h = alloc16(WE), *WihE1l = alloc16(WE);
  u16 *WhhE1h = alloc16(WE), *WhhE1l = alloc16(WE);
  u16 *WihD0h = alloc16(WE), *WihD0l = alloc16(WE);
  u16 *WhhD0h = alloc16(WE), *WhhD0l = alloc16(WE);
  u16 *WihD1h = alloc16(WE), *WihD1l = alloc16(WE);
  u16 *WhhD1h = alloc16(WE), *WhhD1l = alloc16(WE);
  u16 *Wcombh = alloc16(WE), *Wcombl = alloc16(WE);
  u16 *WLh  = alloc16(1024 * 1024), *WLl  = alloc16(1024 * 1024);
  u16 *WLTh = alloc16(1024 * 1024), *WLTl = alloc16(1024 * 1024);
  u16 *XCh = alloc16(16 * HB), *XCl = alloc16(16 * HB);     // x chunk
  u16 *XLh = alloc16(HB), *XLl = alloc16(HB);               // x_last
  u16 *H0ch = alloc16(17 * HB), *H0cl = alloc16(17 * HB);   // h0 ring
  u16 *H1h = alloc16(64 * HB), *H1l = alloc16(64 * HB);     // dec h1 write-once
  u16 *D0h = alloc16(64 * HB), *D0l = alloc16(64 * HB);     // dec d0 write-once
  // zero region
  size_t zbeg = off;
  u16 *zh = alloc16(HB), *zl = alloc16(HB);
  float *c0 = allocf(HB), *c1 = allocf(HB);
  int *barbuf = (int*)(ws + off);
  off = (off + 4096 * sizeof(int) + 255) & ~(size_t)255;
  size_t zend = off;
  // ping-pong h slots (encoder L1)
  u16 *e1h = alloc16(2 * HB), *e1l = alloc16(2 * HB);
  // gate buffers (fp32)
  float *G0 = allocf(1024ull * 4096);   // 16 MB
  float *G1 = allocf(1024ull * 4096);   // 16 MB
  float *Gd0 = allocf(64 * 4096);
  // biases
  float *ebp0 = allocf(4096), *ebp1 = allocf(4096);
  float *dbp0 = allocf(4096), *dbp1 = allocf(4096);
  float *bdec0 = allocf(4096);
  // total ~229 MB

  // 1) zeros (incl. flag lines)
  {
    int n4 = (int)((zend - zbeg) / 16);
    zero_f4<<<dim3((n4 + 255) / 256), dim3(256), 0, stream>>>((float4*)(ws + zbeg), n4);
  }
  // 2) splits
  auto split = [&](const float* src, u16* dh, u16* dl, int n, int mode) {
    split_mat<<<dim3((n + 255) / 256), dim3(256), 0, stream>>>(src, dh, dl, n, mode);
  };
  split(enc_wih,        WihE0h, WihE0l, (int)WE, 2);
  split(enc_whh,        WhhE0h, WhhE0l, (int)WE, 2);
  split(enc_wih + WE,   WihE1h, WihE1l, (int)WE, 2);
  split(enc_whh + WE,   WhhE1h, WhhE1l, (int)WE, 2);
  split(dec_wih,        WihD0h, WihD0l, (int)WE, 2);
  split(dec_whh,        WhhD0h, WhhD0l, (int)WE, 2);
  split(dec_wih + WE,   WihD1h, WihD1l, (int)WE, 2);
  split(dec_whh + WE,   WhhD1h, WhhD1l, (int)WE, 2);
  split(lin_w, WLh,  WLl,  1024 * 1024, 0);
  split(lin_w, WLTh, WLTl, 1024 * 1024, 1);
  split(input_seq + 127ull * HB, XLh, XLl, (int)HB, 0);
  // 3) biases
  bias_perm<<<dim3(16), dim3(256), 0, stream>>>(enc_b,        ebp0);
  bias_perm<<<dim3(16), dim3(256), 0, stream>>>(enc_b + 4096, ebp1);
  bias_perm<<<dim3(16), dim3(256), 0, stream>>>(dec_b,        dbp0);
  bias_perm<<<dim3(16), dim3(256), 0, stream>>>(dec_b + 4096, dbp1);
  bias_comb<<<dim3(4096), dim3(256), 0, stream>>>(dec_b, lin_b, dec_wih, bdec0);
  // 4) Wcomb = WihD0(perm) @ lin_w : M=4096,N=1024 -> 32x8 blocks
  gemm_split<2><<<dim3(32 * 8), dim3(256), 0, stream>>>(
      WihD0h, WihD0l, 1024, WLTh, WLTl, 1024, 1024, 8,
      Wcombh, Wcombl, 1024, nullptr, nullptr, 0, 0);
  // 4b) Gd0 = x_last @ WihD0^T : M=64,N=4096 -> 1x32 blocks
  gemm_split<1><<<dim3(32), dim3(256), 0, stream>>>(
      XLh, XLl, 1024, WihD0h, WihD0l, 1024, 1024, 32,
      nullptr, nullptr, 0, Gd0, nullptr, 4096, 2);

  // 5) encoder: chunk ch: G0 gemm; paired steps L0(ch)+L1(ch-1); G1 gemm.
  for (int ch = 0; ch < 8; ++ch) {
    split(input_seq + (size_t)ch * 16 * HB, XCh, XCl, (int)(16 * HB), 0);
    gemm_split<2><<<dim3(8 * 32), dim3(256), 0, stream>>>(
        XCh, XCl, 1024, WihE0h, WihE0l, 1024, 1024, 32,
        nullptr, nullptr, 0, G0, nullptr, 4096, 2);
    for (int lt = 0; lt < 16; ++lt) {
      int t0 = ch * 16 + lt;               // L0 step index
      int t1 = (ch - 1) * 16 + lt;         // L1 step index (lagged)
      Half A;
      A.Ah = (t0 == 0) ? zh : (lt == 0 ? H0ch + 16ull * HB : H0ch + (size_t)lt * HB);
      A.Al = (t0 == 0) ? zl : (lt == 0 ? H0cl + 16ull * HB : H0cl + (size_t)lt * HB);
      A.Wh = WhhE0h; A.Wl = WhhE0l;
      A.pre = G0 + (size_t)lt * 64 * 4096;
      A.bias = ebp0; A.c = c0;
      A.Hh = H0ch + (size_t)(lt + 1) * HB; A.Hl = H0cl + (size_t)(lt + 1) * HB;
      A.active = 1;
      Half B;
      B.Ah = (t1 == 0) ? zh : e1h + (size_t)((t1 - 1) & 1) * HB;
      B.Al = (t1 == 0) ? zl : e1l + (size_t)((t1 - 1) & 1) * HB;
      B.Wh = WhhE1h; B.Wl = WhhE1l;
      B.pre = G1 + (size_t)lt * 64 * 4096;
      B.bias = ebp1; B.c = c1;
      B.Hh = e1h + (size_t)((t1 >= 0 ? t1 : 0) & 1) * HB;
      B.Hl = e1l + (size_t)((t1 >= 0 ? t1 : 0) & 1) * HB;
      B.active = (ch >= 1) ? 1 : 0;
      lstm_pair<<<dim3(256), dim3(512), 0, stream>>>(A, B);
    }
    gemm_split<2><<<dim3(8 * 32), dim3(256), 0, stream>>>(
        H0ch + HB, H0cl + HB, 1024, WihE1h, WihE1l, 1024, 1024, 32,
        nullptr, nullptr, 0, G1, nullptr, 4096, 2);
  }
  // drain: L1 steps for ch=7 (t1 = 112..127)
  for (int lt = 0; lt < 16; ++lt) {
    int t1 = 112 + lt;
    Half A; A.active = 0;
    A.Ah = zh; A.Al = zl; A.Wh = WhhE0h; A.Wl = WhhE0l;
    A.pre = G0; A.bias = ebp0; A.c = c0; A.Hh = H0ch; A.Hl = H0cl;
    Half B;
    B.Ah = e1h + (size_t)((t1 - 1) & 1) * HB;
    B.Al = e1l + (size_t)((t1 - 1) & 1) * HB;
    B.Wh = WhhE1h; B.Wl = WhhE1l;
    B.pre = G1 + (size_t)lt * 64 * 4096;
    B.bias = ebp1; B.c = c1;
    B.Hh = e1h + (size_t)(t1 & 1) * HB;
    B.Hl = e1l + (size_t)(t1 & 1) * HB;
    B.active = 1;
    lstm_pair<<<dim3(256), dim3(512), 0, stream>>>(A, B);
  }

  // 6) decoder: ONE persistent kernel, layer-split ping-pong, 64 steps
  {
    DecL P;
    P.W00h = Wcombh; P.W00l = Wcombl;
    P.W01h = WhhD0h; P.W01l = WhhD0l;
    P.W10h = WihD1h; P.W10l = WihD1l;
    P.W11h = WhhD1h; P.W11l = WhhD1l;
    P.h0i_h = H0ch + 16ull * HB; P.h0i_l = H0cl + 16ull * HB;
    P.h1i_h = e1h + HB; P.h1i_l = e1l + HB;
    P.zh = zh; P.zl = zl;
    P.Gd0 = Gd0; P.dbp0 = dbp0; P.bdec0 = bdec0; P.dbp1 = dbp1;
    P.c0 = c0; P.c1 = c1;
    P.D0h = D0h; P.D0l = D0l;
    P.H1h = H1h; P.H1l = H1l;
    P.bar = barbuf;
    lstm_dec_layers<<<dim3(256), dim3(512), 0, stream>>>(P);
  }

  // 7) y[b][t][o] = H1[t*64+b][:] . lin_w[o][:] + lin_b[o] : M=4096,N=1024
  gemm_split<2><<<dim3(32 * 8), dim3(256), 0, stream>>>(
      H1h, H1l, 1024, WLh, WLl, 1024, 1024, 8,
      nullptr, nullptr, 0, out, lin_b, 1024, 1);
}

// Round 8
// 6113.119 us; speedup vs baseline: 1.0636x; 1.0023x over previous
//
#include <hip/hip_runtime.h>
#include <math.h>

// ---------------------------------------------------------------------------
// Seq2Seq LSTM (S=128,B=64,I=H=O=1024,L=2,T=64) on gfx950.
// Round 14: force TRUE weight register residency in the decoder.
// Diagnosis: VGPR_Count=128 since R7 == exactly the weight footprint ->
// the compiler was REMATERIALIZING weight loads every t-iteration (128 regs
// can't hold weights+pipeline+addresses). Per hop that re-streams 8MB/XCD of
// weights through a 4MB L2 -> ~10-11us/hop of L3 traffic, the invariant cost
// that five rounds of sync/pipeline changes couldn't move.
// Fix: asm volatile("" : "+v"(w)) on all 32 weight registers after preload --
// opaque to the compiler, so they can't be rematerialized from memory and
// must stay live in registers across all 64 steps (~220 VGPR, still 2
// waves/SIMD). Verification signal: VGPR_Count jumps to ~220-256.
// Everything else unchanged from R13 (layer-split ping-pong, per-wave flag
// waits, 2-batch operand pipeline, write-once D0[t]/H1[t], sc0sc1 producer
// stores, plain consumer loads, no fences). Encoder unchanged.
// ---------------------------------------------------------------------------

typedef unsigned short u16;
typedef short short8 __attribute__((ext_vector_type(8)));
typedef float f32x4 __attribute__((ext_vector_type(4)));

#define MFMA_BF16 __builtin_amdgcn_mfma_f32_16x16x32_bf16

__device__ __forceinline__ u16 f2bf(float x) {
  unsigned u = __builtin_bit_cast(unsigned, x);
  unsigned r = u + 0x7fffu + ((u >> 16) & 1u);
  return (u16)(r >> 16);
}
__device__ __forceinline__ float bf2f(u16 b) {
  return __builtin_bit_cast(float, ((unsigned)b) << 16);
}
__device__ __forceinline__ int permrow(int r) {
  int gate = r >> 10, hc = r & 1023;
  return ((hc >> 2) << 4) + ((hc & 3) << 2) + gate;
}

// write-through store: commits at the device coherence point
__device__ __forceinline__ void st_sc(u16* p, u16 v) {
  unsigned vv = v;
  asm volatile("global_store_short %0, %1, off sc0 sc1" :: "v"(p), "v"(vv) : "memory");
}
// coherent (coherence-point) load/store for flag words
__device__ __forceinline__ int coh_load(const int* p) {
  int v;
  asm volatile("global_load_dword %0, %1, off sc0 sc1\n\ts_waitcnt vmcnt(0)"
               : "=v"(v) : "v"(p) : "memory");
  return v;
}
__device__ __forceinline__ void coh_store(int* p, int v) {
  asm volatile("global_store_dword %0, %1, off sc0 sc1\n\ts_waitcnt vmcnt(0)"
               :: "v"(p), "v"(v) : "memory");
}

// wave-wide flag wait: lane l checks flags[l] and flags[l+64] (128 flags)
__device__ __forceinline__ void wave_wait(const int* fl, int need, int l) {
  const int* p1 = fl + (l << 4);
  while (coh_load(p1) < need) __builtin_amdgcn_s_sleep(1);
  const int* p2 = fl + ((l + 64) << 4);
  while (coh_load(p2) < need) __builtin_amdgcn_s_sleep(1);
}

// ---------------- prep kernels ----------------

// mode 0: plain; mode 1: transpose (1024x1024); mode 2: permute 4096 rows
__global__ void split_mat(const float* __restrict__ src, u16* __restrict__ dh,
                          u16* __restrict__ dl, int n, int mode) {
  int i = blockIdx.x * 256 + threadIdx.x;
  if (i >= n) return;
  float v = src[i];
  u16 hi = f2bf(v);
  u16 lo = f2bf(v - bf2f(hi));
  int r = i >> 10, c = i & 1023;
  int idx = i;
  if (mode == 1) idx = c * 1024 + r;
  else if (mode == 2) idx = permrow(r) * 1024 + c;
  dh[idx] = hi; dl[idx] = lo;
}

__global__ void zero_f4(float4* __restrict__ p, int n) {
  int i = blockIdx.x * 256 + threadIdx.x;
  if (i < n) p[i] = make_float4(0.f, 0.f, 0.f, 0.f);
}

__global__ void bias_perm(const float* __restrict__ in, float* __restrict__ out) {
  int i = blockIdx.x * 256 + threadIdx.x;
  if (i < 4096) out[permrow(i)] = in[i];
}

// bcomb[perm(n)] = dec_b0[n] + sum_k lin_b[k] * dec_wih0[n][k]
__global__ void bias_comb(const float* __restrict__ db0, const float* __restrict__ lb,
                          const float* __restrict__ wih, float* __restrict__ out) {
  __shared__ float red[256];
  int n = blockIdx.x;
  float s = 0.f;
  for (int k = threadIdx.x; k < 1024; k += 256) s += lb[k] * wih[(size_t)n * 1024 + k];
  red[threadIdx.x] = s;
  __syncthreads();
  for (int d = 128; d > 0; d >>= 1) {
    if (threadIdx.x < d) red[threadIdx.x] += red[threadIdx.x + d];
    __syncthreads();
  }
  if (threadIdx.x == 0) out[permrow(n)] = db0[n] + red[0];
}

// ---------- split-bf16 GEMM: C[M,N] = A[M,K] * B[N,K]^T ----------
template<int MT>
__global__ __launch_bounds__(256) void gemm_split(
    const u16* __restrict__ Ah, const u16* __restrict__ Al, int lda,
    const u16* __restrict__ Bh, const u16* __restrict__ Bl, int ldb,
    int K, int gn,
    u16* __restrict__ Ch, u16* __restrict__ Cl, int ldc,
    float* __restrict__ outp, const float* __restrict__ bias, int ldout, int mode) {
  int bm = blockIdx.x / gn, bn = blockIdx.x % gn;
  int l = threadIdx.x & 63, w = threadIdx.x >> 6;
  int n0 = bn * 128 + w * 32;
  int rr = l & 15, ko = (l >> 4) << 3, q = l >> 4;
  int M0 = bm * 64 * MT;
  f32x4 acc[8 * MT] = {};
  for (int kk = 0; kk < K; kk += 32) {
    short8 bh[2], bl[2];
#pragma unroll
    for (int nt = 0; nt < 2; ++nt) {
      size_t bo = (size_t)(n0 + nt * 16 + rr) * ldb + kk + ko;
      bh[nt] = *(const short8*)(Bh + bo);
      bl[nt] = *(const short8*)(Bl + bo);
    }
#pragma unroll
    for (int mt = 0; mt < 4 * MT; ++mt) {
      size_t ao = (size_t)(M0 + mt * 16 + rr) * lda + kk + ko;
      short8 ah = *(const short8*)(Ah + ao);
      short8 al = *(const short8*)(Al + ao);
#pragma unroll
      for (int nt = 0; nt < 2; ++nt) {
        f32x4 t = acc[mt * 2 + nt];
        t = MFMA_BF16(ah, bh[nt], t, 0, 0, 0);
        t = MFMA_BF16(ah, bl[nt], t, 0, 0, 0);
        t = MFMA_BF16(al, bh[nt], t, 0, 0, 0);
        acc[mt * 2 + nt] = t;
      }
    }
  }
#pragma unroll
  for (int mt = 0; mt < 4 * MT; ++mt)
#pragma unroll
    for (int nt = 0; nt < 2; ++nt)
#pragma unroll
      for (int r = 0; r < 4; ++r) {
        int row = M0 + mt * 16 + q * 4 + r;
        int col = n0 + nt * 16 + rr;
        float v = acc[mt * 2 + nt][r];
        if (mode == 0) {
          u16 hh = f2bf(v);
          Ch[(size_t)row * ldc + col] = hh;
          Cl[(size_t)row * ldc + col] = f2bf(v - bf2f(hh));
        } else if (mode == 1) {
          int t = row >> 6, b = row & 63;
          outp[(size_t)b * 65536 + t * 1024 + col] = v + bias[col];
        } else {
          outp[(size_t)row * ldout + col] = v;
        }
      }
}

// ---------------- encoder paired step kernel ----------------

struct Half {
  const u16 *Ah, *Al, *Wh, *Wl;
  const float* pre;    // fp32 [64][4096] gate slab
  const float* bias;   // permuted [4096]
  float* c;
  u16 *Hh, *Hl;
  int active;
};

__global__ __launch_bounds__(512, 1) void lstm_pair(Half hA, Half hB) {
  int j = blockIdx.x;
  Half S = (j < 128) ? hA : hB;
  if (!S.active) return;
  int sub = j & 127;
  int rowblk = ((sub & 7) << 4) | (sub >> 3);   // XCD-pinned, 0..127
  int R = rowblk << 5;                           // 32 rows
  int tid = threadIdx.x;
  int l = tid & 63, w = tid >> 6;
  int rr = l & 15, ko = (l >> 4) << 3, q = l >> 4;
  int kb = w << 7;                               // 128-wide K slice
  const u16* __restrict__ Wh = S.Wh + (size_t)(R + rr) * 1024 + kb + ko;
  const u16* __restrict__ Wl = S.Wl + (size_t)(R + rr) * 1024 + kb + ko;
  const u16* __restrict__ Ah = S.Ah + kb + ko;
  const u16* __restrict__ Al = S.Al + kb + ko;

  f32x4 acc[8] = {};
#pragma unroll
  for (int kk = 0; kk < 128; kk += 32) {
    short8 bh[2], bl[2];
#pragma unroll
    for (int nt = 0; nt < 2; ++nt) {
      bh[nt] = *(const short8*)(Wh + (size_t)(nt << 4) * 1024 + kk);
      bl[nt] = *(const short8*)(Wl + (size_t)(nt << 4) * 1024 + kk);
    }
#pragma unroll
    for (int mt = 0; mt < 4; ++mt) {
      size_t ao = (size_t)((mt << 4) + rr) * 1024 + kk;
      short8 ah = *(const short8*)(Ah + ao);
      short8 al = *(const short8*)(Al + ao);
#pragma unroll
      for (int nt = 0; nt < 2; ++nt) {
        f32x4 t = acc[mt * 2 + nt];
        t = MFMA_BF16(ah, bh[nt], t, 0, 0, 0);
        t = MFMA_BF16(ah, bl[nt], t, 0, 0, 0);
        t = MFMA_BF16(al, bh[nt], t, 0, 0, 0);
        acc[mt * 2 + nt] = t;
      }
    }
  }

  __shared__ float lds[8][64][33];
#pragma unroll
  for (int mt = 0; mt < 4; ++mt)
#pragma unroll
    for (int nt = 0; nt < 2; ++nt)
#pragma unroll
      for (int r = 0; r < 4; ++r)
        lds[w][(mt << 4) + (q << 2) + r][(nt << 4) + rr] = acc[mt * 2 + nt][r];
  __syncthreads();

  int b = tid >> 3, e = tid & 7;
  float g[4];
#pragma unroll
  for (int gt = 0; gt < 4; ++gt) {
    int c = (e << 2) + gt;
    float s = S.bias[R + c] + S.pre[(size_t)b * 4096 + R + c];
#pragma unroll
    for (int ww = 0; ww < 8; ++ww) s += lds[ww][b][c];
    g[gt] = s;
  }
  int hc = (rowblk << 3) + e;
  size_t ci = (size_t)b * 1024 + hc;
  float cold = S.c[ci];
  float is = 1.f / (1.f + expf(-g[0]));
  float fs = 1.f / (1.f + expf(-g[1]));
  float gg = tanhf(g[2]);
  float os = 1.f / (1.f + expf(-g[3]));
  float cn = fs * cold + is * gg;
  S.c[ci] = cn;
  float h = os * tanhf(cn);
  S.Hh[ci] = f2bf(h);
  S.Hl[ci] = f2bf(h - bf2f(f2bf(h)));
}

// ---------------- layer-split ping-pong decoder ----------------
// 256 blocks x 512 thr (1/CU). Blocks 0-127: layer0 (32 perm-rows each);
// 128-255: layer1. Flags: flagA[i] (d0, line i*16), flagB[i] (d1, 2048+i*16).
// Write-once D0[t]/H1[t]; plain consumer loads; no fences.

struct DecL {
  const u16 *W00h, *W00l;    // L0 op0: Wcomb  (A = h1(t-1))   [cross]
  const u16 *W01h, *W01l;    // L0 op1: WhhD0  (A = d0(t-1))   [own]
  const u16 *W10h, *W10l;    // L1 op0: WihD1  (A = d0(t))     [cross]
  const u16 *W11h, *W11l;    // L1 op1: WhhD1  (A = h1(t-1))   [own]
  const u16 *h0i_h, *h0i_l;  // encoder L0 final h
  const u16 *h1i_h, *h1i_l;  // encoder L1 final h
  const u16 *zh, *zl;        // zeros (t=0 L0 op0 operand)
  const float *Gd0, *dbp0, *bdec0, *dbp1;
  const float *c0, *c1;      // encoder final c (read once)
  u16 *D0h, *D0l;            // write-once [64*65536]
  u16 *H1h, *H1l;            // write-once [64*65536]
  int* bar;                  // [4096] pre-zeroed
};

// load batch KI (4 m-tiles x (ah,al)) and MFMA batch KI against weights
#define LOADK(AH, AL, KI)                                              \
  _Pragma("unroll")                                                    \
  for (int mt = 0; mt < 4; ++mt) {                                     \
    size_t ao = (size_t)((mt << 4) + rr) * 1024 + ((KI) << 5);         \
    AH[mt] = *(const short8*)(Ah_ + ao);                               \
    AL[mt] = *(const short8*)(Al_ + ao);                               \
  }
#define MFMAK(AH, AL, KI)                                              \
  _Pragma("unroll")                                                    \
  for (int mt = 0; mt < 4; ++mt) {                                     \
    _Pragma("unroll")                                                  \
    for (int nt = 0; nt < 2; ++nt) {                                   \
      f32x4 tacc = acc[mt * 2 + nt];                                   \
      tacc = MFMA_BF16(AH[mt], wh[nt][KI], tacc, 0, 0, 0);             \
      tacc = MFMA_BF16(AH[mt], wl[nt][KI], tacc, 0, 0, 0);             \
      tacc = MFMA_BF16(AL[mt], wh[nt][KI], tacc, 0, 0, 0);             \
      acc[mt * 2 + nt] = tacc;                                         \
    }                                                                  \
  }

__global__ __launch_bounds__(512, 1) void lstm_dec_layers(DecL D) {
  int j = blockIdx.x;
  int lay = j >> 7;                              // 0 or 1
  int sub = j & 127;
  int rowblk = ((sub & 7) << 4) | (sub >> 3);    // XCD-pinned, 0..127
  int R = rowblk << 5;                           // 32 perm rows
  int tid = threadIdx.x;
  int l = tid & 63, w = tid >> 6;
  int rr = l & 15, ko = (l >> 4) << 3, q = l >> 4;
  int opidx = w >> 2;                            // waves 0-3: op0(cross), 4-7: op1(own)
  int kb = (w & 3) << 8;                         // 256-wide K slice
  int* flagA = D.bar;
  int* flagB = D.bar + 2048;

  // ---- weight fragments: load once, then FORCE register residency ----
  const u16* Wh_ = lay ? (opidx ? D.W11h : D.W10h) : (opidx ? D.W01h : D.W00h);
  const u16* Wl_ = lay ? (opidx ? D.W11l : D.W10l) : (opidx ? D.W01l : D.W00l);
  short8 wh[2][8], wl[2][8];
#pragma unroll
  for (int nt = 0; nt < 2; ++nt)
#pragma unroll
    for (int ki = 0; ki < 8; ++ki) {
      size_t o = (size_t)(R + (nt << 4) + rr) * 1024 + kb + (ki << 5) + ko;
      wh[nt][ki] = *(const short8*)(Wh_ + o);
      wl[nt][ki] = *(const short8*)(Wl_ + o);
    }
  // Opaque asm: values can no longer be rematerialized from memory -> they
  // must live in registers across all 64 steps. (The R7-R13 "weights in
  // VGPRs" was silently undone by compiler remat: VGPR_Count stayed 128.)
#pragma unroll
  for (int nt = 0; nt < 2; ++nt)
#pragma unroll
    for (int ki = 0; ki < 8; ++ki)
      asm volatile("" : "+v"(wh[nt][ki]), "+v"(wl[nt][ki]));

  // ---- tail state: every thread owns (b, e) -> one h cell ----
  int b = tid >> 3, e = tid & 7;
  int hc = (rowblk << 3) + e;
  size_t ci = (size_t)b * 1024 + hc;
  float creg = lay ? D.c1[ci] : D.c0[ci];
  float bT[4], gb0[4];
#pragma unroll
  for (int gt = 0; gt < 4; ++gt) {
    int cc = R + (e << 2) + gt;
    bT[gt] = lay ? D.dbp1[cc] : D.bdec0[cc];
    gb0[gt] = lay ? 0.f : (D.dbp0[cc] + D.Gd0[(size_t)b * 4096 + cc]);
  }

  __shared__ float lds[8][64][33];

  for (int t = 0; t < 64; ++t) {
    // ---- per-wave dependency wait ----
    if (opidx == 1) {
      // own-layer operand (peers' t-1 output): stale flag, near-instant
      if (t > 0) wave_wait(lay ? flagB : flagA, t, l);
    } else {
      // cross-layer operand: fresh flag
      if (lay)            wave_wait(flagA, t + 1, l);
      else if (t > 0)     wave_wait(flagB, t, l);
    }

    // ---- operand selection (all write-once slabs) ----
    const u16 *Aph, *Apl;
    if (!lay) {
      if (opidx == 0) {
        Aph = t ? D.H1h + (size_t)(t - 1) * 65536 : D.zh;
        Apl = t ? D.H1l + (size_t)(t - 1) * 65536 : D.zl;
      } else {
        Aph = t ? D.D0h + (size_t)(t - 1) * 65536 : D.h0i_h;
        Apl = t ? D.D0l + (size_t)(t - 1) * 65536 : D.h0i_l;
      }
    } else {
      if (opidx == 0) {
        Aph = D.D0h + (size_t)t * 65536;
        Apl = D.D0l + (size_t)t * 65536;
      } else {
        Aph = t ? D.H1h + (size_t)(t - 1) * 65536 : D.h1i_h;
        Apl = t ? D.H1l + (size_t)(t - 1) * 65536 : D.h1i_l;
      }
    }
    const u16* __restrict__ Ah_ = Aph + kb + ko;
    const u16* __restrict__ Al_ = Apl + kb + ko;

    // ---- pipelined load + MFMA (1-2 batches of 8x1KB in flight) ----
    f32x4 acc[8] = {};
    {
      short8 xah[4], xal[4], yah[4], yal[4];
      LOADK(xah, xal, 0)
      LOADK(yah, yal, 1)
      MFMAK(xah, xal, 0)
      LOADK(xah, xal, 2)
      MFMAK(yah, yal, 1)
      LOADK(yah, yal, 3)
      MFMAK(xah, xal, 2)
      LOADK(xah, xal, 4)
      MFMAK(yah, yal, 3)
      LOADK(yah, yal, 5)
      MFMAK(xah, xal, 4)
      LOADK(xah, xal, 6)
      MFMAK(yah, yal, 5)
      LOADK(yah, yal, 7)
      MFMAK(xah, xal, 6)
      MFMAK(yah, yal, 7)
    }
#pragma unroll
    for (int mt = 0; mt < 4; ++mt)
#pragma unroll
      for (int nt = 0; nt < 2; ++nt)
#pragma unroll
        for (int r = 0; r < 4; ++r)
          lds[w][(mt << 4) + (q << 2) + r][(nt << 4) + rr] = acc[mt * 2 + nt][r];
    __syncthreads();

    // ---- tail: all 512 threads, one (b, hc) cell each ----
    float g[4];
#pragma unroll
    for (int gt = 0; gt < 4; ++gt) {
      int c = (e << 2) + gt;
      float s = (!lay && t == 0) ? gb0[gt] : bT[gt];
#pragma unroll
      for (int ww = 0; ww < 8; ++ww) s += lds[ww][b][c];
      g[gt] = s;
    }
    float is = 1.f / (1.f + expf(-g[0]));
    float fs = 1.f / (1.f + expf(-g[1]));
    float gg = tanhf(g[2]);
    float os = 1.f / (1.f + expf(-g[3]));
    float cn = fs * creg + is * gg;
    creg = cn;
    float h = os * tanhf(cn);
    u16 hh = f2bf(h), hl = f2bf(h - bf2f(hh));
    size_t oidx = (size_t)t * 65536 + ci;
    if (!lay) { st_sc(D.D0h + oidx, hh); st_sc(D.D0l + oidx, hl); }
    else      { st_sc(D.H1h + oidx, hh); st_sc(D.H1l + oidx, hl); }
    __syncthreads();   // drain all waves' stores + LDS reuse guard
    if (tid == 0) coh_store((lay ? flagB : flagA) + (sub << 4), t + 1);
  }
}

// ---------------- host ----------------

extern "C" void kernel_launch(void* const* d_in, const int* in_sizes, int n_in,
                              void* d_out, int out_size, void* d_ws, size_t ws_size,
                              hipStream_t stream) {
  (void)in_sizes; (void)n_in; (void)out_size; (void)ws_size;
  const float* input_seq = (const float*)d_in[0];
  const float* enc_wih   = (const float*)d_in[1];
  const float* enc_whh   = (const float*)d_in[2];
  const float* enc_b     = (const float*)d_in[3];
  const float* dec_wih   = (const float*)d_in[4];
  const float* dec_whh   = (const float*)d_in[5];
  const float* dec_b     = (const float*)d_in[6];
  const float* lin_w     = (const float*)d_in[7];
  const float* lin_b     = (const float*)d_in[8];
  float* out = (float*)d_out;

  const size_t WE = 4096ull * 1024;
  const size_t HB = 64ull * 1024;
  char* ws = (char*)d_ws;
  size_t off = 0;
  auto alloc16 = [&](size_t elems) {
    u16* p = (u16*)(ws + off);
    off = (off + elems * 2 + 255) & ~(size_t)255;
    return p;
  };
  auto allocf = [&](size_t elems) {
    float* p = (float*)(ws + off);
    off = (off + elems * 4 + 255) & ~(size_t)255;
    return p;
  };

  // weights (permuted rows) split hi/lo: 9 pairs x 16 MB = 144 MB
  u16 *WihE0h = alloc16(WE), *WihE0l = alloc16(WE);
  u16 *WhhE0h = alloc16(WE), *WhhE0l = alloc16(WE);
  u16 *WihE1h = alloc16(WE), *WihE1l = alloc16(WE);
  u16 *WhhE1h = alloc16(WE), *WhhE1l = alloc16(WE);
  u16 *WihD0h = alloc16(WE), *WihD0l = alloc16(WE);
  u16 *WhhD0h = alloc16(WE), *WhhD0l = alloc16(WE);
  u16 *WihD1h = alloc16(WE), *WihD1l = alloc16(WE);
  u16 *WhhD1h = alloc16(WE), *WhhD1l = alloc16(WE);
  u16 *Wcombh = alloc16(WE), *Wcombl = alloc16(WE);
  u16 *WLh  = alloc16(1024 * 1024), *WLl  = alloc16(1024 * 1024);
  u16 *WLTh = alloc16(1024 * 1024), *WLTl = alloc16(1024 * 1024);
  u16 *XCh = alloc16(16 * HB), *XCl = alloc16(16 * HB);     // x chunk
  u16 *XLh = alloc16(HB), *XLl = alloc16(HB);               // x_last
  u16 *H0ch = alloc16(17 * HB), *H0cl = alloc16(17 * HB);   // h0 ring
  u16 *H1h = alloc16(64 * HB), *H1l = alloc16(64 * HB);     // dec h1 write-once
  u16 *D0h = alloc16(64 * HB), *D0l = alloc16(64 * HB);     // dec d0 write-once
  // zero region
  size_t zbeg = off;
  u16 *zh = alloc16(HB), *zl = alloc16(HB);
  float *c0 = allocf(HB), *c1 = allocf(HB);
  int *barbuf = (int*)(ws + off);
  off = (off + 4096 * sizeof(int) + 255) & ~(size_t)255;
  size_t zend = off;
  // ping-pong h slots (encoder L1)
  u16 *e1h = alloc16(2 * HB), *e1l = alloc16(2 * HB);
  // gate buffers (fp32)
  float *G0 = allocf(1024ull * 4096);   // 16 MB
  float *G1 = allocf(1024ull * 4096);   // 16 MB
  float *Gd0 = allocf(64 * 4096);
  // biases
  float *ebp0 = allocf(4096), *ebp1 = allocf(4096);
  float *dbp0 = allocf(4096), *dbp1 = allocf(4096);
  float *bdec0 = allocf(4096);
  // total ~229 MB

  // 1) zeros (incl. flag lines)
  {
    int n4 = (int)((zend - zbeg) / 16);
    zero_f4<<<dim3((n4 + 255) / 256), dim3(256), 0, stream>>>((float4*)(ws + zbeg), n4);
  }
  // 2) splits
  auto split = [&](const float* src, u16* dh, u16* dl, int n, int mode) {
    split_mat<<<dim3((n + 255) / 256), dim3(256), 0, stream>>>(src, dh, dl, n, mode);
  };
  split(enc_wih,        WihE0h, WihE0l, (int)WE, 2);
  split(enc_whh,        WhhE0h, WhhE0l, (int)WE, 2);
  split(enc_wih + WE,   WihE1h, WihE1l, (int)WE, 2);
  split(enc_whh + WE,   WhhE1h, WhhE1l, (int)WE, 2);
  split(dec_wih,        WihD0h, WihD0l, (int)WE, 2);
  split(dec_whh,        WhhD0h, WhhD0l, (int)WE, 2);
  split(dec_wih + WE,   WihD1h, WihD1l, (int)WE, 2);
  split(dec_whh + WE,   WhhD1h, WhhD1l, (int)WE, 2);
  split(lin_w, WLh,  WLl,  1024 * 1024, 0);
  split(lin_w, WLTh, WLTl, 1024 * 1024, 1);
  split(input_seq + 127ull * HB, XLh, XLl, (int)HB, 0);
  // 3) biases
  bias_perm<<<dim3(16), dim3(256), 0, stream>>>(enc_b,        ebp0);
  bias_perm<<<dim3(16), dim3(256), 0, stream>>>(enc_b + 4096, ebp1);
  bias_perm<<<dim3(16), dim3(256), 0, stream>>>(dec_b,        dbp0);
  bias_perm<<<dim3(16), dim3(256), 0, stream>>>(dec_b + 4096, dbp1);
  bias_comb<<<dim3(4096), dim3(256), 0, stream>>>(dec_b, lin_b, dec_wih, bdec0);
  // 4) Wcomb = WihD0(perm) @ lin_w : M=4096,N=1024 -> 32x8 blocks
  gemm_split<2><<<dim3(32 * 8), dim3(256), 0, stream>>>(
      WihD0h, WihD0l, 1024, WLTh, WLTl, 1024, 1024, 8,
      Wcombh, Wcombl, 1024, nullptr, nullptr, 0, 0);
  // 4b) Gd0 = x_last @ WihD0^T : M=64,N=4096 -> 1x32 blocks
  gemm_split<1><<<dim3(32), dim3(256), 0, stream>>>(
      XLh, XLl, 1024, WihD0h, WihD0l, 1024, 1024, 32,
      nullptr, nullptr, 0, Gd0, nullptr, 4096, 2);

  // 5) encoder: chunk ch: G0 gemm; paired steps L0(ch)+L1(ch-1); G1 gemm.
  for (int ch = 0; ch < 8; ++ch) {
    split(input_seq + (size_t)ch * 16 * HB, XCh, XCl, (int)(16 * HB), 0);
    gemm_split<2><<<dim3(8 * 32), dim3(256), 0, stream>>>(
        XCh, XCl, 1024, WihE0h, WihE0l, 1024, 1024, 32,
        nullptr, nullptr, 0, G0, nullptr, 4096, 2);
    for (int lt = 0; lt < 16; ++lt) {
      int t0 = ch * 16 + lt;               // L0 step index
      int t1 = (ch - 1) * 16 + lt;         // L1 step index (lagged)
      Half A;
      A.Ah = (t0 == 0) ? zh : (lt == 0 ? H0ch + 16ull * HB : H0ch + (size_t)lt * HB);
      A.Al = (t0 == 0) ? zl : (lt == 0 ? H0cl + 16ull * HB : H0cl + (size_t)lt * HB);
      A.Wh = WhhE0h; A.Wl = WhhE0l;
      A.pre = G0 + (size_t)lt * 64 * 4096;
      A.bias = ebp0; A.c = c0;
      A.Hh = H0ch + (size_t)(lt + 1) * HB; A.Hl = H0cl + (size_t)(lt + 1) * HB;
      A.active = 1;
      Half B;
      B.Ah = (t1 == 0) ? zh : e1h + (size_t)((t1 - 1) & 1) * HB;
      B.Al = (t1 == 0) ? zl : e1l + (size_t)((t1 - 1) & 1) * HB;
      B.Wh = WhhE1h; B.Wl = WhhE1l;
      B.pre = G1 + (size_t)lt * 64 * 4096;
      B.bias = ebp1; B.c = c1;
      B.Hh = e1h + (size_t)((t1 >= 0 ? t1 : 0) & 1) * HB;
      B.Hl = e1l + (size_t)((t1 >= 0 ? t1 : 0) & 1) * HB;
      B.active = (ch >= 1) ? 1 : 0;
      lstm_pair<<<dim3(256), dim3(512), 0, stream>>>(A, B);
    }
    gemm_split<2><<<dim3(8 * 32), dim3(256), 0, stream>>>(
        H0ch + HB, H0cl + HB, 1024, WihE1h, WihE1l, 1024, 1024, 32,
        nullptr, nullptr, 0, G1, nullptr, 4096, 2);
  }
  // drain: L1 steps for ch=7 (t1 = 112..127)
  for (int lt = 0; lt < 16; ++lt) {
    int t1 = 112 + lt;
    Half A; A.active = 0;
    A.Ah = zh; A.Al = zl; A.Wh = WhhE0h; A.Wl = WhhE0l;
    A.pre = G0; A.bias = ebp0; A.c = c0; A.Hh = H0ch; A.Hl = H0cl;
    Half B;
    B.Ah = e1h + (size_t)((t1 - 1) & 1) * HB;
    B.Al = e1l + (size_t)((t1 - 1) & 1) * HB;
    B.Wh = WhhE1h; B.Wl = WhhE1l;
    B.pre = G1 + (size_t)lt * 64 * 4096;
    B.bias = ebp1; B.c = c1;
    B.Hh = e1h + (size_t)(t1 & 1) * HB;
    B.Hl = e1l + (size_t)(t1 & 1) * HB;
    B.active = 1;
    lstm_pair<<<dim3(256), dim3(512), 0, stream>>>(A, B);
  }

  // 6) decoder: ONE persistent kernel, layer-split ping-pong, 64 steps
  {
    DecL P;
    P.W00h = Wcombh; P.W00l = Wcombl;
    P.W01h = WhhD0h; P.W01l = WhhD0l;
    P.W10h = WihD1h; P.W10l = WihD1l;
    P.W11h = WhhD1h; P.W11l = WhhD1l;
    P.h0i_h = H0ch + 16ull * HB; P.h0i_l = H0cl + 16ull * HB;
    P.h1i_h = e1h + HB; P.h1i_l = e1l + HB;
    P.zh = zh; P.zl = zl;
    P.Gd0 = Gd0; P.dbp0 = dbp0; P.bdec0 = bdec0; P.dbp1 = dbp1;
    P.c0 = c0; P.c1 = c1;
    P.D0h = D0h; P.D0l = D0l;
    P.H1h = H1h; P.H1l = H1l;
    P.bar = barbuf;
    lstm_dec_layers<<<dim3(256), dim3(512), 0, stream>>>(P);
  }

  // 7) y[b][t][o] = H1[t*64+b][:] . lin_w[o][:] + lin_b[o] : M=4096,N=1024
  gemm_split<2><<<dim3(32 * 8), dim3(256), 0, stream>>>(
      H1h, H1l, 1024, WLh, WLl, 1024, 1024, 8,
      nullptr, nullptr, 0, out, lin_b, 1024, 1);
}